// Round 1
// baseline (6064.767 us; speedup 1.0000x reference)
//
#include <hip/hip_runtime.h>
#include <math.h>

#define NN 8192
#define NE 131072
#define TT 12

// ---------------- workspace layout (float offsets) ----------------
static const size_t OFF_HX    = 0;                                // NN*64
static const size_t OFF_HE0   = OFF_HX    + (size_t)NN*64;        // NE*64
static const size_t OFF_HE1   = OFF_HE0   + (size_t)NE*64;        // NE*64
static const size_t OFF_A2    = OFF_HE1   + (size_t)NE*64;        // NN*64
static const size_t OFF_A3    = OFF_A2    + (size_t)NN*64;
static const size_t OFF_A5    = OFF_A3    + (size_t)NN*64;
static const size_t OFF_A6    = OFF_A5    + (size_t)NN*64;
static const size_t OFF_SENT  = OFF_A6    + (size_t)NN*64;
static const size_t OFF_RECVD = OFF_SENT  + (size_t)NN*64;
static const size_t OFF_NEWN  = OFF_RECVD + (size_t)NN*64;        // NN * (TT*64) : [m][t*64+h]
static const size_t OFF_GL    = OFF_NEWN  + (size_t)NN*TT*64;     // 64
static const size_t OFF_CBE   = OFF_GL    + 64;                   // 64
static const size_t OFF_CBN   = OFF_CBE   + 64;                   // 64
static const size_t OFF_ESUM  = OFF_CBN   + 64;                   // 64
static const size_t OFF_NSUM  = OFF_ESUM  + 64;                   // 64

// ---------------- init: zero hx + he0, copy global_attr -> gl ----------------
__global__ void init_kernel(float* __restrict__ ws, const float* __restrict__ global_attr) {
  size_t total = (size_t)NN*64 + (size_t)NE*64;   // hx and he0 are contiguous
  for (size_t i = (size_t)blockIdx.x*blockDim.x + threadIdx.x; i < total;
       i += (size_t)gridDim.x*blockDim.x)
    ws[OFF_HX + i] = 0.f;
  if (blockIdx.x == 0 && threadIdx.x < 64)
    ws[OFF_GL + threadIdx.x] = global_attr[threadIdx.x];
}

// ---------------- prep for step 0: cb_e = W7@gl + b_eb, cb_n = Wg@gl + b_nb ----------------
__global__ void prep_kernel(const float* __restrict__ w_eb, const float* __restrict__ b_eb,
                            const float* __restrict__ w_nb, const float* __restrict__ b_nb,
                            float* __restrict__ ws) {
  int h = threadIdx.x;   // 64 threads
  float se = b_eb[h], sn = b_nb[h];
  for (int c = 0; c < 64; ++c) {
    float g = ws[OFF_GL + c];
    se += w_eb[h*448 + 384 + c] * g;
    sn += w_nb[h*320 + 256 + c] * g;
  }
  ws[OFF_CBE + h] = se;
  ws[OFF_CBN + h] = sn;
  ws[OFF_ESUM + h] = 0.f;
  ws[OFF_NSUM + h] = 0.f;
}

// ---------------- GRU over T steps + output head -> pred ----------------
__global__ __launch_bounds__(256) void gru_his_kernel(
    const float* __restrict__ node_attrs, const float* __restrict__ w_ih,
    const float* __restrict__ w_hh, const float* __restrict__ b_ih,
    const float* __restrict__ b_hh, const float* __restrict__ w_lout,
    const float* __restrict__ b_lout, float* __restrict__ pred_out)
{
  __shared__ float Whh[192*65];
  __shared__ float wih_s[192], bih_s[192], bhh_s[192], wlo_s[64];
  int tid = threadIdx.x;
  for (int i = tid; i < 192*64; i += 256) {
    int rr = i >> 6, k = i & 63;
    Whh[rr*65 + k] = w_hh[i];
  }
  for (int i = tid; i < 192; i += 256) { wih_s[i] = w_ih[i]; bih_s[i] = b_ih[i]; bhh_s[i] = b_hh[i]; }
  if (tid < 64) wlo_s[tid] = w_lout[tid];
  __syncthreads();
  int lane = tid & 63, wv = tid >> 6;
  int n = blockIdx.x*4 + wv;
  int j = lane;
  float h = 0.f;
  for (int t = 0; t < TT; ++t) {
    float x = node_attrs[t*NN + n];
    float ar = 0.f, az = 0.f, an = 0.f;
    #pragma unroll 16
    for (int k = 0; k < 64; ++k) {
      float hk = __shfl(h, k);
      ar += hk * Whh[j*65 + k];
      az += hk * Whh[(64+j)*65 + k];
      an += hk * Whh[(128+j)*65 + k];
    }
    float xr = x*wih_s[j]      + bih_s[j];
    float xz = x*wih_s[64+j]   + bih_s[64+j];
    float xn = x*wih_s[128+j]  + bih_s[128+j];
    float r  = 1.f/(1.f + expf(-(xr + ar + bhh_s[j])));
    float z  = 1.f/(1.f + expf(-(xz + az + bhh_s[64+j])));
    float nnv = tanhf(xn + r*(an + bhh_s[128+j]));
    h = (1.f - z)*nnv + z*h;
  }
  float v = h * wlo_s[j];
  #pragma unroll
  for (int off = 32; off >= 1; off >>= 1) v += __shfl_xor(v, off);
  if (lane == 0) pred_out[n] = v + b_lout[0];
}

// ---------------- per-step node-side projections A2=W2@nx A3=W3@nx A5=W5@hx A6=W6@hx ----------------
__global__ __launch_bounds__(256) void node_proj_kernel(
    const float* __restrict__ node_attrs, const float* __restrict__ w_eb,
    const float* __restrict__ w_node_enc, const float* __restrict__ b_node_enc,
    float* __restrict__ ws, int t)
{
  __shared__ float W2[64*65], W3[64*65], W5[64*65], W6[64*65];
  __shared__ float wne[64], bne[64];
  int tid = threadIdx.x;
  for (int i = tid; i < 64*64; i += 256) {
    int h = i >> 6, c = i & 63;
    W2[h*65+c] = w_eb[h*448 + 64  + c];
    W3[h*65+c] = w_eb[h*448 + 128 + c];
    W5[h*65+c] = w_eb[h*448 + 256 + c];
    W6[h*65+c] = w_eb[h*448 + 320 + c];
  }
  if (tid < 64) { wne[tid] = w_node_enc[tid]; bne[tid] = b_node_enc[tid]; }
  __syncthreads();
  int lane = tid & 63, wv = tid >> 6;
  float* A2 = ws + OFF_A2; float* A3 = ws + OFF_A3;
  float* A5 = ws + OFF_A5; float* A6 = ws + OFF_A6;
  float* hx = ws + OFF_HX;
  float* sent = ws + OFF_SENT; float* recvd = ws + OFF_RECVD;
  for (int q = 0; q < 4; ++q) {
    int n = blockIdx.x*16 + wv*4 + q;
    float na = node_attrs[t*NN + n];
    float nx = fmaxf(na*wne[lane] + bne[lane], 0.f);
    float hv = hx[n*64 + lane];
    float a2 = 0.f, a3 = 0.f, a5 = 0.f, a6 = 0.f;
    #pragma unroll 16
    for (int c = 0; c < 64; ++c) {
      float nxc = __shfl(nx, c);
      float hvc = __shfl(hv, c);
      int wi = lane*65 + c;
      a2 += W2[wi]*nxc; a3 += W3[wi]*nxc;
      a5 += W5[wi]*hvc; a6 += W6[wi]*hvc;
    }
    A2[n*64+lane] = a2; A3[n*64+lane] = a3;
    A5[n*64+lane] = a5; A6[n*64+lane] = a6;
    sent[n*64+lane] = 0.f; recvd[n*64+lane] = 0.f;
  }
}

// ---------------- per-step edge block ----------------
__global__ __launch_bounds__(256) void edge_kernel(
    const float* __restrict__ edge_attrs, const int* __restrict__ edge_index,
    const float* __restrict__ w_eb, const float* __restrict__ w_edge_enc,
    const float* __restrict__ b_edge_enc, float* __restrict__ ws,
    const float* __restrict__ he_cur, float* __restrict__ he_next, int t)
{
  __shared__ float W1[64*65], W4[64*65];
  __shared__ float wee[64], bee[64], cbe[64];
  int tid = threadIdx.x;
  for (int i = tid; i < 64*64; i += 256) {
    int h = i >> 6, c = i & 63;
    W1[h*65+c] = w_eb[h*448 + c];
    W4[h*65+c] = w_eb[h*448 + 192 + c];
  }
  if (tid < 64) { wee[tid] = w_edge_enc[tid]; bee[tid] = b_edge_enc[tid]; cbe[tid] = ws[OFF_CBE + tid]; }
  __syncthreads();
  int lane = tid & 63, wv = tid >> 6;
  const int* sendi = edge_index;
  const int* recvi = edge_index + NE;
  const float* A2 = ws + OFF_A2; const float* A3 = ws + OFF_A3;
  const float* A5 = ws + OFF_A5; const float* A6 = ws + OFF_A6;
  float* sent = ws + OFF_SENT; float* recvd = ws + OFF_RECVD;
  for (int q = 0; q < 16; ++q) {
    int e = blockIdx.x*64 + wv*16 + q;
    float ea = edge_attrs[t*NE + e];
    float eev = fmaxf(ea*wee[lane] + bee[lane], 0.f);
    float hev = he_cur[(size_t)e*64 + lane];
    float acc = 0.f;
    #pragma unroll 16
    for (int c = 0; c < 64; ++c) {
      float eec = __shfl(eev, c);
      float hec = __shfl(hev, c);
      int wi = lane*65 + c;
      acc += W1[wi]*eec + W4[wi]*hec;
    }
    int s = sendi[e], r = recvi[e];
    acc += A2[s*64+lane] + A3[r*64+lane] + A5[s*64+lane] + A6[r*64+lane] + cbe[lane];
    float ne = fmaxf(acc, 0.f);
    he_next[(size_t)e*64 + lane] = ne;
    atomicAdd(&sent[s*64+lane], ne);
    atomicAdd(&recvd[r*64+lane], ne);
  }
}

// ---------------- generic (rows x 64) column-sum into out64 via atomics ----------------
__global__ __launch_bounds__(256) void reduce_rows_kernel(
    const float* __restrict__ data, int rows, float* __restrict__ out64)
{
  int h = threadIdx.x & 63;
  int sub = threadIdx.x >> 6;
  float s = 0.f;
  for (int r = blockIdx.x*4 + sub; r < rows; r += gridDim.x*4)
    s += data[(size_t)r*64 + h];
  __shared__ float red[4][64];
  red[sub][h] = s;
  __syncthreads();
  if (sub == 0) atomicAdd(&out64[h], red[0][h] + red[1][h] + red[2][h] + red[3][h]);
}

// ---------------- per-step node block: new_n, tds, hx update, newn_all store ----------------
__global__ __launch_bounds__(256) void node_kernel(
    const float* __restrict__ node_attrs, const float* __restrict__ w_nb,
    const float* __restrict__ w_node_enc, const float* __restrict__ b_node_enc,
    float* __restrict__ ws, float* __restrict__ tds_out, int t)
{
  __shared__ float B1[64*65], B2[64*65], B3[64*65], B4[64*65];
  __shared__ float wne[64], bne[64], cbn[64];
  int tid = threadIdx.x;
  for (int i = tid; i < 64*64; i += 256) {
    int h = i >> 6, c = i & 63;
    B1[h*65+c] = w_nb[h*320 + c];          // nx
    B2[h*65+c] = w_nb[h*320 + 64  + c];    // hx
    B3[h*65+c] = w_nb[h*320 + 128 + c];    // recvd
    B4[h*65+c] = w_nb[h*320 + 192 + c];    // sent
  }
  if (tid < 64) { wne[tid] = w_node_enc[tid]; bne[tid] = b_node_enc[tid]; cbn[tid] = ws[OFF_CBN + tid]; }
  __syncthreads();
  int lane = tid & 63, wv = tid >> 6;
  float* hx = ws + OFF_HX;
  const float* sent = ws + OFF_SENT; const float* recvd = ws + OFF_RECVD;
  float* newn = ws + OFF_NEWN;
  for (int q = 0; q < 4; ++q) {
    int n = blockIdx.x*16 + wv*4 + q;
    float na = node_attrs[t*NN + n];
    float nx = fmaxf(na*wne[lane] + bne[lane], 0.f);
    float hv = hx[n*64 + lane];
    float rc = recvd[n*64 + lane];
    float st = sent[n*64 + lane];
    float acc = 0.f;
    #pragma unroll 16
    for (int c = 0; c < 64; ++c) {
      float nxc = __shfl(nx, c);
      float hvc = __shfl(hv, c);
      float rcc = __shfl(rc, c);
      float stc = __shfl(st, c);
      int wi = lane*65 + c;
      acc += B1[wi]*nxc + B2[wi]*hvc + B3[wi]*rcc + B4[wi]*stc;
    }
    acc += cbn[lane];
    float nn = fmaxf(acc, 0.f);
    tds_out[(size_t)t*NN*64 + (size_t)n*64 + lane] = nn - hv;
    hx[n*64 + lane] = nn;
    newn[(size_t)n*(TT*64) + t*64 + lane] = nn;
  }
}

// ---------------- per-step global block (+ next step cb prep + zero sums) ----------------
__global__ void global_prep_kernel(
    const float* __restrict__ w_gb, const float* __restrict__ b_gb,
    const float* __restrict__ w_eb, const float* __restrict__ b_eb,
    const float* __restrict__ w_nb, const float* __restrict__ b_nb,
    float* __restrict__ ws)
{
  int h = threadIdx.x;   // 64 threads
  __shared__ float gin[192];
  __shared__ float gs[64];
  gin[h]       = ws[OFF_NSUM + h] * (1.0f/NN);
  gin[64 + h]  = ws[OFF_ESUM + h] * (1.0f/NE);
  gin[128 + h] = ws[OFF_GL + h];
  __syncthreads();
  float a = b_gb[h];
  for (int c = 0; c < 192; ++c) a += w_gb[h*192 + c] * gin[c];
  float g = fmaxf(a, 0.f);
  gs[h] = g;
  __syncthreads();
  ws[OFF_GL + h] = g;
  float se = b_eb[h], sn = b_nb[h];
  for (int c = 0; c < 64; ++c) {
    float gc = gs[c];
    se += w_eb[h*448 + 384 + c] * gc;
    sn += w_nb[h*320 + 256 + c] * gc;
  }
  ws[OFF_CBE + h] = se;
  ws[OFF_CBN + h] = sn;
  ws[OFF_ESUM + h] = 0.f;
  ws[OFF_NSUM + h] = 0.f;
}

// ---------------- final batched GEMM: sds = coeff * (sp_L @ newn_all) ----------------
// A: 8192x8192 row-major.  B: 8192 x 768 row-major ([m][t*64+h]).
// C written directly to sds region: out[t*NN*64 + m*64 + h].
__global__ __launch_bounds__(256) void sds_gemm_kernel(
    const float* __restrict__ A, const float* __restrict__ B,
    float* __restrict__ C, const float* __restrict__ coeff)
{
  __shared__ float As[16][68];   // [k][m]
  __shared__ float Bs[16][68];   // [k][n]
  int tid = threadIdx.x;
  int m0 = blockIdx.x * 64;
  int n0 = blockIdx.y * 64;
  int tm = (tid >> 4) * 4;       // 0..60
  int tn = (tid & 15) * 4;       // 0..60
  int arow = tid >> 2;           // 0..63
  int acol = (tid & 3) * 4;      // 0..12
  int brow = tid >> 4;           // 0..15
  int bcol = (tid & 15) * 4;     // 0..60
  float acc[4][4] = {};
  const float cf = coeff[0];
  for (int k0 = 0; k0 < NN; k0 += 16) {
    float4 av = *(const float4*)&A[(size_t)(m0 + arow)*NN + k0 + acol];
    float4 bv = *(const float4*)&B[(size_t)(k0 + brow)*(TT*64) + n0 + bcol];
    __syncthreads();
    As[acol+0][arow] = av.x; As[acol+1][arow] = av.y;
    As[acol+2][arow] = av.z; As[acol+3][arow] = av.w;
    *(float4*)&Bs[brow][bcol] = bv;
    __syncthreads();
    #pragma unroll
    for (int k = 0; k < 16; ++k) {
      float4 a4 = *(const float4*)&As[k][tm];
      float4 b4 = *(const float4*)&Bs[k][tn];
      acc[0][0] += a4.x*b4.x; acc[0][1] += a4.x*b4.y; acc[0][2] += a4.x*b4.z; acc[0][3] += a4.x*b4.w;
      acc[1][0] += a4.y*b4.x; acc[1][1] += a4.y*b4.y; acc[1][2] += a4.y*b4.z; acc[1][3] += a4.y*b4.w;
      acc[2][0] += a4.z*b4.x; acc[2][1] += a4.z*b4.y; acc[2][2] += a4.z*b4.z; acc[2][3] += a4.z*b4.w;
      acc[3][0] += a4.w*b4.x; acc[3][1] += a4.w*b4.y; acc[3][2] += a4.w*b4.z; acc[3][3] += a4.w*b4.w;
    }
  }
  #pragma unroll
  for (int i = 0; i < 4; ++i) {
    int m = m0 + tm + i;
    #pragma unroll
    for (int j = 0; j < 4; ++j) {
      int n = n0 + tn + j;
      int tt = n >> 6, h = n & 63;
      C[(size_t)tt*NN*64 + (size_t)m*64 + h] = cf * acc[i][j];
    }
  }
}

// ---------------- host ----------------
extern "C" void kernel_launch(void* const* d_in, const int* in_sizes, int n_in,
                              void* d_out, int out_size, void* d_ws, size_t ws_size,
                              hipStream_t stream) {
  const float* node_attrs  = (const float*)d_in[0];
  const float* edge_attrs  = (const float*)d_in[1];
  const float* global_attr = (const float*)d_in[2];
  const float* sp_L        = (const float*)d_in[3];
  const float* coeff       = (const float*)d_in[4];
  const float* w_edge_enc  = (const float*)d_in[5];
  const float* b_edge_enc  = (const float*)d_in[6];
  const float* w_node_enc  = (const float*)d_in[7];
  const float* b_node_enc  = (const float*)d_in[8];
  const float* w_eb        = (const float*)d_in[9];
  const float* b_eb        = (const float*)d_in[10];
  const float* w_nb        = (const float*)d_in[11];
  const float* b_nb        = (const float*)d_in[12];
  const float* w_gb        = (const float*)d_in[13];
  const float* b_gb        = (const float*)d_in[14];
  const float* gru_w_ih    = (const float*)d_in[15];
  const float* gru_w_hh    = (const float*)d_in[16];
  const float* gru_b_ih    = (const float*)d_in[17];
  const float* gru_b_hh    = (const float*)d_in[18];
  const float* w_lout      = (const float*)d_in[19];
  const float* b_lout      = (const float*)d_in[20];
  const int*   edge_index  = (const int*)d_in[21];

  float* ws  = (float*)d_ws;
  float* out = (float*)d_out;
  float* pred_out = out;                              // NN
  float* tds_out  = out + NN;                         // TT*NN*64
  float* sds_out  = tds_out + (size_t)TT*NN*64;       // TT*NN*64

  hipLaunchKernelGGL(init_kernel, dim3(1024), dim3(256), 0, stream, ws, global_attr);
  hipLaunchKernelGGL(gru_his_kernel, dim3(NN/4), dim3(256), 0, stream,
                     node_attrs, gru_w_ih, gru_w_hh, gru_b_ih, gru_b_hh,
                     w_lout, b_lout, pred_out);
  hipLaunchKernelGGL(prep_kernel, dim3(1), dim3(64), 0, stream, w_eb, b_eb, w_nb, b_nb, ws);

  for (int t = 0; t < TT; ++t) {
    float* he_cur  = ws + ((t & 1) ? OFF_HE1 : OFF_HE0);
    float* he_next = ws + ((t & 1) ? OFF_HE0 : OFF_HE1);
    hipLaunchKernelGGL(node_proj_kernel, dim3(NN/16), dim3(256), 0, stream,
                       node_attrs, w_eb, w_node_enc, b_node_enc, ws, t);
    hipLaunchKernelGGL(edge_kernel, dim3(NE/64), dim3(256), 0, stream,
                       edge_attrs, edge_index, w_eb, w_edge_enc, b_edge_enc,
                       ws, he_cur, he_next, t);
    hipLaunchKernelGGL(reduce_rows_kernel, dim3(256), dim3(256), 0, stream,
                       he_next, (int)NE, ws + OFF_ESUM);
    hipLaunchKernelGGL(node_kernel, dim3(NN/16), dim3(256), 0, stream,
                       node_attrs, w_nb, w_node_enc, b_node_enc, ws, tds_out, t);
    hipLaunchKernelGGL(reduce_rows_kernel, dim3(256), dim3(256), 0, stream,
                       ws + OFF_HX, (int)NN, ws + OFF_NSUM);
    hipLaunchKernelGGL(global_prep_kernel, dim3(1), dim3(64), 0, stream,
                       w_gb, b_gb, w_eb, b_eb, w_nb, b_nb, ws);
  }

  hipLaunchKernelGGL(sds_gemm_kernel, dim3(NN/64, (TT*64)/64), dim3(256), 0, stream,
                     sp_L, ws + OFF_NEWN, sds_out, coeff);
}

// Round 3
// 3332.393 us; speedup vs baseline: 1.8199x; 1.8199x over previous
//
#include <hip/hip_runtime.h>
#include <math.h>

#define NN 8192
#define NE 131072
#define TT 12

typedef __attribute__((ext_vector_type(8))) short bf16x8;
typedef __attribute__((ext_vector_type(4))) float f32x4;

// ---------------- workspace layout (float offsets) ----------------
static const size_t OFF_HX    = 0;                                // NN*64
static const size_t OFF_HE0   = OFF_HX    + (size_t)NN*64;        // NE*64
static const size_t OFF_HE1   = OFF_HE0   + (size_t)NE*64;        // NE*64
static const size_t OFF_A25   = OFF_HE1   + (size_t)NE*64;        // NN*64
static const size_t OFF_A36   = OFF_A25   + (size_t)NN*64;
static const size_t OFF_SENT  = OFF_A36   + (size_t)NN*64;
static const size_t OFF_RECVD = OFF_SENT  + (size_t)NN*64;
static const size_t OFF_NEWN  = OFF_RECVD + (size_t)NN*64;        // ushort region: newn_T [TT*64][NN] bf16
static const size_t OFF_GL    = OFF_NEWN  + (size_t)NN*TT*32;     // 64
static const size_t OFF_CBE   = OFF_GL    + 64;
static const size_t OFF_CBN   = OFF_CBE   + 64;
static const size_t OFF_ESUM  = OFF_CBN   + 64;
static const size_t OFF_NSUM  = OFF_ESUM  + 64;
static const size_t OFF_EBF   = OFF_NSUM  + 64;                   // ushort region: 24576 shorts (12288 floats)

// ---------------- bf16 helpers ----------------
__device__ inline unsigned short f2bf(float x) {
  union { float f; unsigned u; } v; v.f = x;
  unsigned r = v.u + 0x7fffu + ((v.u >> 16) & 1u);
  return (unsigned short)(r >> 16);
}
__device__ inline float bf2f(unsigned short h) {
  union { unsigned u; float f; } v; v.u = ((unsigned)h) << 16;
  return v.f;
}
__device__ inline void split8(const float* x, bf16x8& hi, bf16x8& lo) {
  #pragma unroll
  for (int j = 0; j < 8; ++j) {
    unsigned short h = f2bf(x[j]);
    hi[j] = (short)h;
    lo[j] = (short)f2bf(x[j] - bf2f(h));
  }
}

// ---------------- init: zero hx + he0, copy global_attr -> gl ----------------
__global__ void init_kernel(float* __restrict__ ws, const float* __restrict__ global_attr) {
  size_t total = (size_t)NN*64 + (size_t)NE*64;   // hx and he0 contiguous
  for (size_t i = (size_t)blockIdx.x*blockDim.x + threadIdx.x; i < total;
       i += (size_t)gridDim.x*blockDim.x)
    ws[OFF_HX + i] = 0.f;
  if (blockIdx.x == 0 && threadIdx.x < 64)
    ws[OFF_GL + threadIdx.x] = global_attr[threadIdx.x];
}

// ---------------- prep: cb_e/cb_n for step 0 ----------------
__global__ void prep_kernel(const float* __restrict__ w_eb, const float* __restrict__ b_eb,
                            const float* __restrict__ w_nb, const float* __restrict__ b_nb,
                            float* __restrict__ ws) {
  int h = threadIdx.x;   // 64 threads
  float se = b_eb[h], sn = b_nb[h];
  for (int c = 0; c < 64; ++c) {
    float g = ws[OFF_GL + c];
    se += w_eb[h*448 + 384 + c] * g;
    sn += w_nb[h*320 + 256 + c] * g;
  }
  ws[OFF_CBE + h] = se;
  ws[OFF_CBN + h] = sn;
  ws[OFF_ESUM + h] = 0.f;
  ws[OFF_NSUM + h] = 0.f;
}

// ---------------- build MFMA B-frag table for edge block ----------------
// segs: 0:(eeH,W1H) 1:(eeL,W1H) 2:(eeH,W1L) 3:(heH,W4H) 4:(heL,W4H) 5:(heH,W4L)
__global__ void ebfrag_kernel(const float* __restrict__ w_eb, unsigned short* __restrict__ ebf) {
  int idx = blockIdx.x*256 + threadIdx.x;  // 6*64*64 = 24576
  if (idx >= 24576) return;
  int s = idx >> 12;        // 0..5
  int rem = idx & 4095;
  int k = rem >> 6;         // 0..63
  int n = rem & 63;
  float w = (s < 3) ? w_eb[n*448 + k] : w_eb[n*448 + 192 + k];
  unsigned short h = f2bf(w);
  unsigned short l = f2bf(w - bf2f(h));
  unsigned short val = (s == 2 || s == 5) ? l : h;
  int kh = k >> 5, q = (k >> 3) & 3, j = k & 7;
  int nt = n >> 4, col = n & 15;
  int lane = q*16 + col;
  ebf[(((size_t)(s*2 + kh)*4 + nt)*64 + lane)*8 + j] = val;
}

// ---------------- GRU over T steps + output head -> pred ----------------
__global__ __launch_bounds__(256) void gru_his_kernel(
    const float* __restrict__ node_attrs, const float* __restrict__ w_ih,
    const float* __restrict__ w_hh, const float* __restrict__ b_ih,
    const float* __restrict__ b_hh, const float* __restrict__ w_lout,
    const float* __restrict__ b_lout, float* __restrict__ pred_out)
{
  __shared__ float Whh[192*65];
  __shared__ float wih_s[192], bih_s[192], bhh_s[192], wlo_s[64];
  int tid = threadIdx.x;
  for (int i = tid; i < 192*64; i += 256) {
    int rr = i >> 6, k = i & 63;
    Whh[rr*65 + k] = w_hh[i];
  }
  for (int i = tid; i < 192; i += 256) { wih_s[i] = w_ih[i]; bih_s[i] = b_ih[i]; bhh_s[i] = b_hh[i]; }
  if (tid < 64) wlo_s[tid] = w_lout[tid];
  __syncthreads();
  int lane = tid & 63, wv = tid >> 6;
  int n = blockIdx.x*4 + wv;
  int j = lane;
  float h = 0.f;
  for (int t = 0; t < TT; ++t) {
    float x = node_attrs[t*NN + n];
    float ar = 0.f, az = 0.f, an = 0.f;
    #pragma unroll 16
    for (int k = 0; k < 64; ++k) {
      float hk = __shfl(h, k);
      ar += hk * Whh[j*65 + k];
      az += hk * Whh[(64+j)*65 + k];
      an += hk * Whh[(128+j)*65 + k];
    }
    float xr = x*wih_s[j]      + bih_s[j];
    float xz = x*wih_s[64+j]   + bih_s[64+j];
    float xn = x*wih_s[128+j]  + bih_s[128+j];
    float r  = 1.f/(1.f + expf(-(xr + ar + bhh_s[j])));
    float z  = 1.f/(1.f + expf(-(xz + az + bhh_s[64+j])));
    float nnv = tanhf(xn + r*(an + bhh_s[128+j]));
    h = (1.f - z)*nnv + z*h;
  }
  float v = h * wlo_s[j];
  #pragma unroll
  for (int off = 32; off >= 1; off >>= 1) v += __shfl_xor(v, off);
  if (lane == 0) pred_out[n] = v + b_lout[0];
}

// ---------------- per-step node-side projections A25 = W2@nx+W5@hx, A36 = W3@nx+W6@hx ----------------
__global__ __launch_bounds__(256) void node_proj_kernel(
    const float* __restrict__ node_attrs, const float* __restrict__ w_eb,
    const float* __restrict__ w_node_enc, const float* __restrict__ b_node_enc,
    float* __restrict__ ws, int t)
{
  __shared__ float W2[64*65], W3[64*65], W5[64*65], W6[64*65];
  __shared__ float wne[64], bne[64];
  int tid = threadIdx.x;
  for (int i = tid; i < 64*64; i += 256) {
    int h = i >> 6, c = i & 63;
    W2[h*65+c] = w_eb[h*448 + 64  + c];
    W3[h*65+c] = w_eb[h*448 + 128 + c];
    W5[h*65+c] = w_eb[h*448 + 256 + c];
    W6[h*65+c] = w_eb[h*448 + 320 + c];
  }
  if (tid < 64) { wne[tid] = w_node_enc[tid]; bne[tid] = b_node_enc[tid]; }
  __syncthreads();
  int lane = tid & 63, wv = tid >> 6;
  float* A25 = ws + OFF_A25; float* A36 = ws + OFF_A36;
  float* hx = ws + OFF_HX;
  float* sent = ws + OFF_SENT; float* recvd = ws + OFF_RECVD;
  for (int q = 0; q < 4; ++q) {
    int n = blockIdx.x*16 + wv*4 + q;
    float na = node_attrs[t*NN + n];
    float nx = fmaxf(na*wne[lane] + bne[lane], 0.f);
    float hv = hx[n*64 + lane];
    float a2 = 0.f, a3 = 0.f, a5 = 0.f, a6 = 0.f;
    #pragma unroll 16
    for (int c = 0; c < 64; ++c) {
      float nxc = __shfl(nx, c);
      float hvc = __shfl(hv, c);
      int wi = lane*65 + c;
      a2 += W2[wi]*nxc; a3 += W3[wi]*nxc;
      a5 += W5[wi]*hvc; a6 += W6[wi]*hvc;
    }
    A25[n*64+lane] = a2 + a5; A36[n*64+lane] = a3 + a6;
    sent[n*64+lane] = 0.f; recvd[n*64+lane] = 0.f;
  }
}

// ---------------- per-step edge block via MFMA (hi/lo split, K=384) ----------------
__global__ __launch_bounds__(256) void edge_mfma_kernel(
    const float* __restrict__ edge_attrs, const int* __restrict__ edge_index,
    const float* __restrict__ w_edge_enc, const float* __restrict__ b_edge_enc,
    const unsigned short* __restrict__ ebf, float* __restrict__ ws,
    const float* __restrict__ he_cur, float* __restrict__ he_next, int t)
{
  __shared__ unsigned short Bs[12*4*64*8];   // 48 KB, same layout as ebf
  __shared__ float wee_s[64], bee_s[64], cbe_s[64];
  int tid = threadIdx.x;
  for (int i = tid; i < 3072; i += 256)
    ((uint4*)Bs)[i] = ((const uint4*)ebf)[i];
  if (tid < 64) { wee_s[tid]=w_edge_enc[tid]; bee_s[tid]=b_edge_enc[tid]; cbe_s[tid]=ws[OFF_CBE+tid]; }
  __syncthreads();
  int lane = tid & 63, wv = tid >> 6;
  int m = lane & 15, q = lane >> 4;
  int e0 = blockIdx.x * 64;
  int em = e0 + wv*16 + m;
  // ---- A frags (in registers, no LDS) ----
  float ea = edge_attrs[(size_t)t*NE + em];
  bf16x8 eeH[2], eeL[2], heH[2], heL[2];
  #pragma unroll
  for (int kh = 0; kh < 2; ++kh) {
    float xs[8];
    #pragma unroll
    for (int j = 0; j < 8; ++j) {
      int c = kh*32 + q*8 + j;
      xs[j] = fmaxf(ea*wee_s[c] + bee_s[c], 0.f);
    }
    split8(xs, eeH[kh], eeL[kh]);
    float4 h0 = *(const float4*)(he_cur + (size_t)em*64 + kh*32 + q*8);
    float4 h1 = *(const float4*)(he_cur + (size_t)em*64 + kh*32 + q*8 + 4);
    float hs[8] = {h0.x,h0.y,h0.z,h0.w,h1.x,h1.y,h1.z,h1.w};
    split8(hs, heH[kh], heL[kh]);
  }
  // ---- MFMA: 12 K-blocks x 4 N-tiles ----
  f32x4 acc[4] = {};
  #pragma unroll
  for (int s = 0; s < 6; ++s) {
    #pragma unroll
    for (int kh = 0; kh < 2; ++kh) {
      bf16x8 a = (s==0||s==2) ? eeH[kh] : (s==1) ? eeL[kh] : (s==4) ? heL[kh] : heH[kh];
      const bf16x8* bp = (const bf16x8*)(Bs + (size_t)((s*2+kh)*4*64)*8);
      #pragma unroll
      for (int nt = 0; nt < 4; ++nt) {
        bf16x8 b = bp[nt*64 + lane];
        acc[nt] = __builtin_amdgcn_mfma_f32_16x16x32_bf16(a, b, acc[nt], 0, 0, 0);
      }
    }
  }
  // ---- epilogue: gathers + relu + stores + atomics ----
  const int* sendi = edge_index;
  const int* recvi = edge_index + NE;
  const float* A25 = ws + OFF_A25;
  const float* A36 = ws + OFF_A36;
  float* sent = ws + OFF_SENT; float* recvd = ws + OFF_RECVD;
  int col = lane & 15;
  #pragma unroll
  for (int r = 0; r < 4; ++r) {
    int e = e0 + wv*16 + q*4 + r;
    int se = sendi[e], re = recvi[e];
    #pragma unroll
    for (int nt = 0; nt < 4; ++nt) {
      int h = nt*16 + col;
      float v = acc[nt][r] + A25[(size_t)se*64 + h] + A36[(size_t)re*64 + h] + cbe_s[h];
      v = fmaxf(v, 0.f);
      he_next[(size_t)e*64 + h] = v;
      atomicAdd(&sent[(size_t)se*64 + h], v);
      atomicAdd(&recvd[(size_t)re*64 + h], v);
    }
  }
}

// ---------------- generic (rows x 64) column-sum into out64 via atomics ----------------
__global__ __launch_bounds__(256) void reduce_rows_kernel(
    const float* __restrict__ data, int rows, float* __restrict__ out64)
{
  int h = threadIdx.x & 63;
  int sub = threadIdx.x >> 6;
  float s = 0.f;
  for (int r = blockIdx.x*4 + sub; r < rows; r += gridDim.x*4)
    s += data[(size_t)r*64 + h];
  __shared__ float red[4][64];
  red[sub][h] = s;
  __syncthreads();
  if (sub == 0) atomicAdd(&out64[h], red[0][h] + red[1][h] + red[2][h] + red[3][h]);
}

// ---------------- per-step node block: new_n, tds, hx update, newn_T bf16 store ----------------
__global__ __launch_bounds__(256) void node_kernel(
    const float* __restrict__ node_attrs, const float* __restrict__ w_nb,
    const float* __restrict__ w_node_enc, const float* __restrict__ b_node_enc,
    float* __restrict__ ws, float* __restrict__ tds_out, int t)
{
  __shared__ float B1[64*65], B2[64*65], B3[64*65], B4[64*65];
  __shared__ float wne[64], bne[64], cbn[64];
  int tid = threadIdx.x;
  for (int i = tid; i < 64*64; i += 256) {
    int h = i >> 6, c = i & 63;
    B1[h*65+c] = w_nb[h*320 + c];          // nx
    B2[h*65+c] = w_nb[h*320 + 64  + c];    // hx
    B3[h*65+c] = w_nb[h*320 + 128 + c];    // recvd
    B4[h*65+c] = w_nb[h*320 + 192 + c];    // sent
  }
  if (tid < 64) { wne[tid] = w_node_enc[tid]; bne[tid] = b_node_enc[tid]; cbn[tid] = ws[OFF_CBN + tid]; }
  __syncthreads();
  int lane = tid & 63, wv = tid >> 6;
  float* hx = ws + OFF_HX;
  const float* sent = ws + OFF_SENT; const float* recvd = ws + OFF_RECVD;
  unsigned short* newnT = (unsigned short*)(ws + OFF_NEWN);
  for (int q = 0; q < 4; ++q) {
    int n = blockIdx.x*16 + wv*4 + q;
    float na = node_attrs[t*NN + n];
    float nx = fmaxf(na*wne[lane] + bne[lane], 0.f);
    float hv = hx[n*64 + lane];
    float rc = recvd[n*64 + lane];
    float st = sent[n*64 + lane];
    float acc = 0.f;
    #pragma unroll 16
    for (int c = 0; c < 64; ++c) {
      float nxc = __shfl(nx, c);
      float hvc = __shfl(hv, c);
      float rcc = __shfl(rc, c);
      float stc = __shfl(st, c);
      int wi = lane*65 + c;
      acc += B1[wi]*nxc + B2[wi]*hvc + B3[wi]*rcc + B4[wi]*stc;
    }
    acc += cbn[lane];
    float nn = fmaxf(acc, 0.f);
    tds_out[(size_t)t*NN*64 + (size_t)n*64 + lane] = nn - hv;
    hx[n*64 + lane] = nn;
    newnT[(size_t)(t*64 + lane)*NN + n] = f2bf(nn);   // transposed bf16 for sds GEMM
  }
}

// ---------------- per-step global block (+ next step cb prep + zero sums) ----------------
__global__ void global_prep_kernel(
    const float* __restrict__ w_gb, const float* __restrict__ b_gb,
    const float* __restrict__ w_eb, const float* __restrict__ b_eb,
    const float* __restrict__ w_nb, const float* __restrict__ b_nb,
    float* __restrict__ ws)
{
  int h = threadIdx.x;   // 64 threads
  __shared__ float gin[192];
  __shared__ float gs[64];
  gin[h]       = ws[OFF_NSUM + h] * (1.0f/NN);
  gin[64 + h]  = ws[OFF_ESUM + h] * (1.0f/NE);
  gin[128 + h] = ws[OFF_GL + h];
  __syncthreads();
  float a = b_gb[h];
  for (int c = 0; c < 192; ++c) a += w_gb[h*192 + c] * gin[c];
  float g = fmaxf(a, 0.f);
  gs[h] = g;
  __syncthreads();
  ws[OFF_GL + h] = g;
  float se = b_eb[h], sn = b_nb[h];
  for (int c = 0; c < 64; ++c) {
    float gc = gs[c];
    se += w_eb[h*448 + 384 + c] * gc;
    sn += w_nb[h*320 + 256 + c] * gc;
  }
  ws[OFF_CBE + h] = se;
  ws[OFF_CBN + h] = sn;
  ws[OFF_ESUM + h] = 0.f;
  ws[OFF_NSUM + h] = 0.f;
}

// ---------------- final GEMM via MFMA: sds = coeff * (sp_L @ newn) ----------------
// A: sp_L fp32 [8192x8192], converted to bf16 in-registers.
// Bt: newn_T bf16 [768][8192] (row n = t*64+h, col k = node).
// C: sds_out [t][m][h].  Block = 128x128 tile, 4 waves (2x2), wave = 64x64.
__global__ __launch_bounds__(256) void sds_mfma_kernel(
    const float* __restrict__ A, const unsigned short* __restrict__ Bt,
    float* __restrict__ C, const float* __restrict__ coeff)
{
  int tid = threadIdx.x;
  int lane = tid & 63, wv = tid >> 6;
  int wm = wv >> 1, wn = wv & 1;
  int q = lane >> 4, l16 = lane & 15;
  int m0 = blockIdx.y*128 + wm*64;
  int n0 = blockIdx.x*128 + wn*64;
  f32x4 acc[4][4] = {};
  for (int k0 = 0; k0 < NN; k0 += 32) {
    bf16x8 af[4], bfr[4];
    #pragma unroll
    for (int i = 0; i < 4; ++i) {
      const float* ap = A + (size_t)(m0 + i*16 + l16)*NN + k0 + q*8;
      float4 a0 = *(const float4*)ap;
      float4 a1 = *(const float4*)(ap + 4);
      float xs[8] = {a0.x,a0.y,a0.z,a0.w,a1.x,a1.y,a1.z,a1.w};
      #pragma unroll
      for (int j = 0; j < 8; ++j) af[i][j] = (short)f2bf(xs[j]);
      bfr[i] = *(const bf16x8*)(Bt + (size_t)(n0 + i*16 + l16)*NN + k0 + q*8);
    }
    #pragma unroll
    for (int mi = 0; mi < 4; ++mi)
      #pragma unroll
      for (int ni = 0; ni < 4; ++ni)
        acc[mi][ni] = __builtin_amdgcn_mfma_f32_16x16x32_bf16(af[mi], bfr[ni], acc[mi][ni], 0, 0, 0);
  }
  float cf = coeff[0];
  #pragma unroll
  for (int mi = 0; mi < 4; ++mi) {
    int row = m0 + mi*16 + q*4;
    #pragma unroll
    for (int ni = 0; ni < 4; ++ni) {
      int cn = n0 + ni*16 + l16;
      int tt = cn >> 6, h = cn & 63;
      #pragma unroll
      for (int r = 0; r < 4; ++r)
        C[(size_t)tt*NN*64 + (size_t)(row + r)*64 + h] = cf * acc[mi][ni][r];
    }
  }
}

// ---------------- host ----------------
extern "C" void kernel_launch(void* const* d_in, const int* in_sizes, int n_in,
                              void* d_out, int out_size, void* d_ws, size_t ws_size,
                              hipStream_t stream) {
  const float* node_attrs  = (const float*)d_in[0];
  const float* edge_attrs  = (const float*)d_in[1];
  const float* global_attr = (const float*)d_in[2];
  const float* sp_L        = (const float*)d_in[3];
  const float* coeff       = (const float*)d_in[4];
  const float* w_edge_enc  = (const float*)d_in[5];
  const float* b_edge_enc  = (const float*)d_in[6];
  const float* w_node_enc  = (const float*)d_in[7];
  const float* b_node_enc  = (const float*)d_in[8];
  const float* w_eb        = (const float*)d_in[9];
  const float* b_eb        = (const float*)d_in[10];
  const float* w_nb        = (const float*)d_in[11];
  const float* b_nb        = (const float*)d_in[12];
  const float* w_gb        = (const float*)d_in[13];
  const float* b_gb        = (const float*)d_in[14];
  const float* gru_w_ih    = (const float*)d_in[15];
  const float* gru_w_hh    = (const float*)d_in[16];
  const float* gru_b_ih    = (const float*)d_in[17];
  const float* gru_b_hh    = (const float*)d_in[18];
  const float* w_lout      = (const float*)d_in[19];
  const float* b_lout      = (const float*)d_in[20];
  const int*   edge_index  = (const int*)d_in[21];

  float* ws  = (float*)d_ws;
  float* out = (float*)d_out;
  float* pred_out = out;                              // NN
  float* tds_out  = out + NN;                         // TT*NN*64
  float* sds_out  = tds_out + (size_t)TT*NN*64;       // TT*NN*64
  unsigned short* ebf = (unsigned short*)(ws + OFF_EBF);

  hipLaunchKernelGGL(init_kernel, dim3(1024), dim3(256), 0, stream, ws, global_attr);
  hipLaunchKernelGGL(ebfrag_kernel, dim3(96), dim3(256), 0, stream, w_eb, ebf);
  hipLaunchKernelGGL(gru_his_kernel, dim3(NN/4), dim3(256), 0, stream,
                     node_attrs, gru_w_ih, gru_w_hh, gru_b_ih, gru_b_hh,
                     w_lout, b_lout, pred_out);
  hipLaunchKernelGGL(prep_kernel, dim3(1), dim3(64), 0, stream, w_eb, b_eb, w_nb, b_nb, ws);

  for (int t = 0; t < TT; ++t) {
    float* he_cur  = ws + ((t & 1) ? OFF_HE1 : OFF_HE0);
    float* he_next = ws + ((t & 1) ? OFF_HE0 : OFF_HE1);
    hipLaunchKernelGGL(node_proj_kernel, dim3(NN/16), dim3(256), 0, stream,
                       node_attrs, w_eb, w_node_enc, b_node_enc, ws, t);
    hipLaunchKernelGGL(edge_mfma_kernel, dim3(NE/64), dim3(256), 0, stream,
                       edge_attrs, edge_index, w_edge_enc, b_edge_enc,
                       ebf, ws, he_cur, he_next, t);
    hipLaunchKernelGGL(reduce_rows_kernel, dim3(256), dim3(256), 0, stream,
                       he_next, (int)NE, ws + OFF_ESUM);
    hipLaunchKernelGGL(node_kernel, dim3(NN/16), dim3(256), 0, stream,
                       node_attrs, w_nb, w_node_enc, b_node_enc, ws, tds_out, t);
    hipLaunchKernelGGL(reduce_rows_kernel, dim3(256), dim3(256), 0, stream,
                       ws + OFF_HX, (int)NN, ws + OFF_NSUM);
    hipLaunchKernelGGL(global_prep_kernel, dim3(1), dim3(64), 0, stream,
                       w_gb, b_gb, w_eb, b_eb, w_nb, b_nb, ws);
  }

  hipLaunchKernelGGL(sds_mfma_kernel, dim3(6, 64), dim3(256), 0, stream,
                     sp_L, (const unsigned short*)(ws + OFF_NEWN), sds_out, coeff);
}

// Round 4
// 2922.933 us; speedup vs baseline: 2.0749x; 1.1401x over previous
//
#include <hip/hip_runtime.h>
#include <math.h>

#define NN 8192
#define NE 131072
#define TT 12

typedef __attribute__((ext_vector_type(8))) short bf16x8;
typedef __attribute__((ext_vector_type(4))) float f32x4;

// ---------------- workspace layout (float offsets) ----------------
static const size_t OFF_HX    = 0;                                // NN*64
static const size_t OFF_HE0   = OFF_HX    + (size_t)NN*64;        // NE*64 (reused as sds partial P0 after loop)
static const size_t OFF_HE1   = OFF_HE0   + (size_t)NE*64;        // NE*64 (reused as sds partial P1 after loop)
static const size_t OFF_A25   = OFF_HE1   + (size_t)NE*64;        // NN*64
static const size_t OFF_A36   = OFF_A25   + (size_t)NN*64;
static const size_t OFF_SENT  = OFF_A36   + (size_t)NN*64;
static const size_t OFF_RECVD = OFF_SENT  + (size_t)NN*64;
static const size_t OFF_NEWN  = OFF_RECVD + (size_t)NN*64;        // ushort region: newn_T [TT*64][NN] bf16
static const size_t OFF_GL    = OFF_NEWN  + (size_t)NN*TT*32;     // 64
static const size_t OFF_CBE   = OFF_GL    + 64;
static const size_t OFF_CBN   = OFF_CBE   + 64;
static const size_t OFF_ESUM  = OFF_CBN   + 64;
static const size_t OFF_NSUM  = OFF_ESUM  + 64;
static const size_t OFF_EBF   = OFF_NSUM  + 64;                   // ushort region: 24576 shorts

// ---------------- bf16 helpers ----------------
__device__ inline unsigned short f2bf(float x) {
  union { float f; unsigned u; } v; v.f = x;
  unsigned r = v.u + 0x7fffu + ((v.u >> 16) & 1u);
  return (unsigned short)(r >> 16);
}
__device__ inline float bf2f(unsigned short h) {
  union { unsigned u; float f; } v; v.u = ((unsigned)h) << 16;
  return v.f;
}
__device__ inline void split8(const float* x, bf16x8& hi, bf16x8& lo) {
  #pragma unroll
  for (int j = 0; j < 8; ++j) {
    unsigned short h = f2bf(x[j]);
    hi[j] = (short)h;
    lo[j] = (short)f2bf(x[j] - bf2f(h));
  }
}

// ---------------- init: zero hx + he0, copy global_attr -> gl ----------------
__global__ void init_kernel(float* __restrict__ ws, const float* __restrict__ global_attr) {
  size_t total = (size_t)NN*64 + (size_t)NE*64;   // hx and he0 contiguous
  for (size_t i = (size_t)blockIdx.x*blockDim.x + threadIdx.x; i < total;
       i += (size_t)gridDim.x*blockDim.x)
    ws[OFF_HX + i] = 0.f;
  if (blockIdx.x == 0 && threadIdx.x < 64)
    ws[OFF_GL + threadIdx.x] = global_attr[threadIdx.x];
}

// ---------------- prep: cb_e/cb_n for step 0 ----------------
__global__ void prep_kernel(const float* __restrict__ w_eb, const float* __restrict__ b_eb,
                            const float* __restrict__ w_nb, const float* __restrict__ b_nb,
                            float* __restrict__ ws) {
  int h = threadIdx.x;   // 64 threads
  float se = b_eb[h], sn = b_nb[h];
  for (int c = 0; c < 64; ++c) {
    float g = ws[OFF_GL + c];
    se += w_eb[h*448 + 384 + c] * g;
    sn += w_nb[h*320 + 256 + c] * g;
  }
  ws[OFF_CBE + h] = se;
  ws[OFF_CBN + h] = sn;
  ws[OFF_ESUM + h] = 0.f;
  ws[OFF_NSUM + h] = 0.f;
}

// ---------------- build MFMA B-frag table for edge block ----------------
// segs: 0:(eeH,W1H) 1:(eeL,W1H) 2:(eeH,W1L) 3:(heH,W4H) 4:(heL,W4H) 5:(heH,W4L)
__global__ void ebfrag_kernel(const float* __restrict__ w_eb, unsigned short* __restrict__ ebf) {
  int idx = blockIdx.x*256 + threadIdx.x;  // 6*64*64 = 24576
  if (idx >= 24576) return;
  int s = idx >> 12;        // 0..5
  int rem = idx & 4095;
  int k = rem >> 6;         // 0..63
  int n = rem & 63;
  float w = (s < 3) ? w_eb[n*448 + k] : w_eb[n*448 + 192 + k];
  unsigned short h = f2bf(w);
  unsigned short l = f2bf(w - bf2f(h));
  unsigned short val = (s == 2 || s == 5) ? l : h;
  int kh = k >> 5, q = (k >> 3) & 3, j = k & 7;
  int nt = n >> 4, col = n & 15;
  int lane = q*16 + col;
  ebf[(((size_t)(s*2 + kh)*4 + nt)*64 + lane)*8 + j] = val;
}

// ---------------- GRU over T steps + output head -> pred ----------------
__global__ __launch_bounds__(256) void gru_his_kernel(
    const float* __restrict__ node_attrs, const float* __restrict__ w_ih,
    const float* __restrict__ w_hh, const float* __restrict__ b_ih,
    const float* __restrict__ b_hh, const float* __restrict__ w_lout,
    const float* __restrict__ b_lout, float* __restrict__ pred_out)
{
  __shared__ float Whh[192*65];
  __shared__ float wih_s[192], bih_s[192], bhh_s[192], wlo_s[64];
  int tid = threadIdx.x;
  for (int i = tid; i < 192*64; i += 256) {
    int rr = i >> 6, k = i & 63;
    Whh[rr*65 + k] = w_hh[i];
  }
  for (int i = tid; i < 192; i += 256) { wih_s[i] = w_ih[i]; bih_s[i] = b_ih[i]; bhh_s[i] = b_hh[i]; }
  if (tid < 64) wlo_s[tid] = w_lout[tid];
  __syncthreads();
  int lane = tid & 63, wv = tid >> 6;
  int n = blockIdx.x*4 + wv;
  int j = lane;
  float h = 0.f;
  for (int t = 0; t < TT; ++t) {
    float x = node_attrs[t*NN + n];
    float ar = 0.f, az = 0.f, an = 0.f;
    #pragma unroll 16
    for (int k = 0; k < 64; ++k) {
      float hk = __shfl(h, k);
      ar += hk * Whh[j*65 + k];
      az += hk * Whh[(64+j)*65 + k];
      an += hk * Whh[(128+j)*65 + k];
    }
    float xr = x*wih_s[j]      + bih_s[j];
    float xz = x*wih_s[64+j]   + bih_s[64+j];
    float xn = x*wih_s[128+j]  + bih_s[128+j];
    float r  = 1.f/(1.f + expf(-(xr + ar + bhh_s[j])));
    float z  = 1.f/(1.f + expf(-(xz + az + bhh_s[64+j])));
    float nnv = tanhf(xn + r*(an + bhh_s[128+j]));
    h = (1.f - z)*nnv + z*h;
  }
  float v = h * wlo_s[j];
  #pragma unroll
  for (int off = 32; off >= 1; off >>= 1) v += __shfl_xor(v, off);
  if (lane == 0) pred_out[n] = v + b_lout[0];
}

// ---------------- per-step node-side projections A25 = W2@nx+W5@hx, A36 = W3@nx+W6@hx ----------------
__global__ __launch_bounds__(256) void node_proj_kernel(
    const float* __restrict__ node_attrs, const float* __restrict__ w_eb,
    const float* __restrict__ w_node_enc, const float* __restrict__ b_node_enc,
    float* __restrict__ ws, int t)
{
  __shared__ float W2[64*65], W3[64*65], W5[64*65], W6[64*65];
  __shared__ float wne[64], bne[64];
  int tid = threadIdx.x;
  for (int i = tid; i < 64*64; i += 256) {
    int h = i >> 6, c = i & 63;
    W2[h*65+c] = w_eb[h*448 + 64  + c];
    W3[h*65+c] = w_eb[h*448 + 128 + c];
    W5[h*65+c] = w_eb[h*448 + 256 + c];
    W6[h*65+c] = w_eb[h*448 + 320 + c];
  }
  if (tid < 64) { wne[tid] = w_node_enc[tid]; bne[tid] = b_node_enc[tid]; }
  __syncthreads();
  int lane = tid & 63, wv = tid >> 6;
  float* A25 = ws + OFF_A25; float* A36 = ws + OFF_A36;
  float* hx = ws + OFF_HX;
  float* sent = ws + OFF_SENT; float* recvd = ws + OFF_RECVD;
  for (int q = 0; q < 4; ++q) {
    int n = blockIdx.x*16 + wv*4 + q;
    float na = node_attrs[t*NN + n];
    float nx = fmaxf(na*wne[lane] + bne[lane], 0.f);
    float hv = hx[n*64 + lane];
    float a2 = 0.f, a3 = 0.f, a5 = 0.f, a6 = 0.f;
    #pragma unroll 16
    for (int c = 0; c < 64; ++c) {
      float nxc = __shfl(nx, c);
      float hvc = __shfl(hv, c);
      int wi = lane*65 + c;
      a2 += W2[wi]*nxc; a3 += W3[wi]*nxc;
      a5 += W5[wi]*hvc; a6 += W6[wi]*hvc;
    }
    A25[n*64+lane] = a2 + a5; A36[n*64+lane] = a3 + a6;
    sent[n*64+lane] = 0.f; recvd[n*64+lane] = 0.f;
  }
}

// ---------------- per-step edge block via MFMA (hi/lo split, K=384) + fused ESUM ----------------
__global__ __launch_bounds__(256) void edge_mfma_kernel(
    const float* __restrict__ edge_attrs, const int* __restrict__ edge_index,
    const float* __restrict__ w_edge_enc, const float* __restrict__ b_edge_enc,
    const unsigned short* __restrict__ ebf, float* __restrict__ ws,
    const float* __restrict__ he_cur, float* __restrict__ he_next, int t)
{
  __shared__ unsigned short Bs[12*4*64*8];   // 48 KB, same layout as ebf
  __shared__ float wee_s[64], bee_s[64], cbe_s[64];
  __shared__ float esum_s[64];
  int tid = threadIdx.x;
  for (int i = tid; i < 3072; i += 256)
    ((uint4*)Bs)[i] = ((const uint4*)ebf)[i];
  if (tid < 64) { wee_s[tid]=w_edge_enc[tid]; bee_s[tid]=b_edge_enc[tid]; cbe_s[tid]=ws[OFF_CBE+tid]; esum_s[tid]=0.f; }
  __syncthreads();
  int lane = tid & 63, wv = tid >> 6;
  int m = lane & 15, q = lane >> 4;
  int e0 = blockIdx.x * 64;
  int em = e0 + wv*16 + m;
  // ---- A frags (in registers, no LDS) ----
  float ea = edge_attrs[(size_t)t*NE + em];
  bf16x8 eeH[2], eeL[2], heH[2], heL[2];
  #pragma unroll
  for (int kh = 0; kh < 2; ++kh) {
    float xs[8];
    #pragma unroll
    for (int j = 0; j < 8; ++j) {
      int c = kh*32 + q*8 + j;
      xs[j] = fmaxf(ea*wee_s[c] + bee_s[c], 0.f);
    }
    split8(xs, eeH[kh], eeL[kh]);
    float4 h0 = *(const float4*)(he_cur + (size_t)em*64 + kh*32 + q*8);
    float4 h1 = *(const float4*)(he_cur + (size_t)em*64 + kh*32 + q*8 + 4);
    float hs[8] = {h0.x,h0.y,h0.z,h0.w,h1.x,h1.y,h1.z,h1.w};
    split8(hs, heH[kh], heL[kh]);
  }
  // ---- MFMA: 12 K-blocks x 4 N-tiles ----
  f32x4 acc[4] = {};
  #pragma unroll
  for (int s = 0; s < 6; ++s) {
    #pragma unroll
    for (int kh = 0; kh < 2; ++kh) {
      bf16x8 a = (s==0||s==2) ? eeH[kh] : (s==1) ? eeL[kh] : (s==4) ? heL[kh] : heH[kh];
      const bf16x8* bp = (const bf16x8*)(Bs + (size_t)((s*2+kh)*4*64)*8);
      #pragma unroll
      for (int nt = 0; nt < 4; ++nt) {
        bf16x8 b = bp[nt*64 + lane];
        acc[nt] = __builtin_amdgcn_mfma_f32_16x16x32_bf16(a, b, acc[nt], 0, 0, 0);
      }
    }
  }
  // ---- epilogue: gathers + relu + stores + atomics + fused esum ----
  const int* sendi = edge_index;
  const int* recvi = edge_index + NE;
  const float* A25 = ws + OFF_A25;
  const float* A36 = ws + OFF_A36;
  float* sent = ws + OFF_SENT; float* recvd = ws + OFF_RECVD;
  int col = lane & 15;
  float part[4] = {0.f, 0.f, 0.f, 0.f};
  #pragma unroll
  for (int r = 0; r < 4; ++r) {
    int e = e0 + wv*16 + q*4 + r;
    int se = sendi[e], re = recvi[e];
    #pragma unroll
    for (int nt = 0; nt < 4; ++nt) {
      int h = nt*16 + col;
      float v = acc[nt][r] + A25[(size_t)se*64 + h] + A36[(size_t)re*64 + h] + cbe_s[h];
      v = fmaxf(v, 0.f);
      he_next[(size_t)e*64 + h] = v;
      atomicAdd(&sent[(size_t)se*64 + h], v);
      atomicAdd(&recvd[(size_t)re*64 + h], v);
      part[nt] += v;
    }
  }
  #pragma unroll
  for (int nt = 0; nt < 4; ++nt) {
    part[nt] += __shfl_xor(part[nt], 16);
    part[nt] += __shfl_xor(part[nt], 32);
  }
  if (q == 0) {
    #pragma unroll
    for (int nt = 0; nt < 4; ++nt)
      atomicAdd(&esum_s[nt*16 + col], part[nt]);
  }
  __syncthreads();
  if (tid < 64) atomicAdd(&ws[OFF_ESUM + tid], esum_s[tid]);
}

// ---------------- per-step node block: new_n, tds, hx update, newn_T bf16, fused NSUM ----------------
__global__ __launch_bounds__(256) void node_kernel(
    const float* __restrict__ node_attrs, const float* __restrict__ w_nb,
    const float* __restrict__ w_node_enc, const float* __restrict__ b_node_enc,
    float* __restrict__ ws, float* __restrict__ tds_out, int t)
{
  __shared__ float B1[64*65], B2[64*65], B3[64*65], B4[64*65];
  __shared__ float wne[64], bne[64], cbn[64];
  __shared__ float nsum_s[4][64];
  int tid = threadIdx.x;
  for (int i = tid; i < 64*64; i += 256) {
    int h = i >> 6, c = i & 63;
    B1[h*65+c] = w_nb[h*320 + c];          // nx
    B2[h*65+c] = w_nb[h*320 + 64  + c];    // hx
    B3[h*65+c] = w_nb[h*320 + 128 + c];    // recvd
    B4[h*65+c] = w_nb[h*320 + 192 + c];    // sent
  }
  if (tid < 64) { wne[tid] = w_node_enc[tid]; bne[tid] = b_node_enc[tid]; cbn[tid] = ws[OFF_CBN + tid]; }
  __syncthreads();
  int lane = tid & 63, wv = tid >> 6;
  float* hx = ws + OFF_HX;
  const float* sent = ws + OFF_SENT; const float* recvd = ws + OFF_RECVD;
  unsigned short* newnT = (unsigned short*)(ws + OFF_NEWN);
  float npart = 0.f;
  for (int q = 0; q < 4; ++q) {
    int n = blockIdx.x*16 + wv*4 + q;
    float na = node_attrs[t*NN + n];
    float nx = fmaxf(na*wne[lane] + bne[lane], 0.f);
    float hv = hx[n*64 + lane];
    float rc = recvd[n*64 + lane];
    float st = sent[n*64 + lane];
    float acc = 0.f;
    #pragma unroll 16
    for (int c = 0; c < 64; ++c) {
      float nxc = __shfl(nx, c);
      float hvc = __shfl(hv, c);
      float rcc = __shfl(rc, c);
      float stc = __shfl(st, c);
      int wi = lane*65 + c;
      acc += B1[wi]*nxc + B2[wi]*hvc + B3[wi]*rcc + B4[wi]*stc;
    }
    acc += cbn[lane];
    float nn = fmaxf(acc, 0.f);
    tds_out[(size_t)t*NN*64 + (size_t)n*64 + lane] = nn - hv;
    hx[n*64 + lane] = nn;
    newnT[(size_t)(t*64 + lane)*NN + n] = f2bf(nn);   // transposed bf16 for sds GEMM
    npart += nn;
  }
  nsum_s[wv][lane] = npart;
  __syncthreads();
  if (tid < 64)
    atomicAdd(&ws[OFF_NSUM + tid],
              nsum_s[0][tid] + nsum_s[1][tid] + nsum_s[2][tid] + nsum_s[3][tid]);
}

// ---------------- per-step global block (+ next step cb prep + zero sums) ----------------
__global__ void global_prep_kernel(
    const float* __restrict__ w_gb, const float* __restrict__ b_gb,
    const float* __restrict__ w_eb, const float* __restrict__ b_eb,
    const float* __restrict__ w_nb, const float* __restrict__ b_nb,
    float* __restrict__ ws)
{
  int h = threadIdx.x;   // 64 threads
  __shared__ float gin[192];
  __shared__ float gs[64];
  gin[h]       = ws[OFF_NSUM + h] * (1.0f/NN);
  gin[64 + h]  = ws[OFF_ESUM + h] * (1.0f/NE);
  gin[128 + h] = ws[OFF_GL + h];
  __syncthreads();
  float a = b_gb[h];
  for (int c = 0; c < 192; ++c) a += w_gb[h*192 + c] * gin[c];
  float g = fmaxf(a, 0.f);
  gs[h] = g;
  __syncthreads();
  ws[OFF_GL + h] = g;
  float se = b_eb[h], sn = b_nb[h];
  for (int c = 0; c < 64; ++c) {
    float gc = gs[c];
    se += w_eb[h*448 + 384 + c] * gc;
    sn += w_nb[h*320 + 256 + c] * gc;
  }
  ws[OFF_CBE + h] = se;
  ws[OFF_CBN + h] = sn;
  ws[OFF_ESUM + h] = 0.f;
  ws[OFF_NSUM + h] = 0.f;
}

// ---------------- sds GEMM via MFMA, split-K=2, A read once ----------------
// A: sp_L fp32 [8192x8192]. Bt: newn_T bf16 [768][8192]. P: partial [t][m][h] fp32.
// Block: 64m x 768n, 512 threads = 8 waves (wave = 64m x 96n).
// grid = (ksplit=2, mblocks=128). A k-slice staged fp32->bf16 into double-buffered LDS.
__global__ __launch_bounds__(512) void sds_mfma_kernel(
    const float* __restrict__ A, const unsigned short* __restrict__ Bt,
    float* __restrict__ P0, float* __restrict__ P1)
{
  __shared__ unsigned short Asm[2][64][72];   // padded stride 72 (144B: 16B-aligned, conflict-free)
  int tid = threadIdx.x;
  int lane = tid & 63, wv = tid >> 6;
  int q = lane >> 4, l16 = lane & 15;
  int m0 = blockIdx.y * 64;
  int kbase = blockIdx.x * (NN/2);
  float* P = (blockIdx.x == 0) ? P0 : P1;

  // staging role: row sr (0..63), col group sc (0,8,..,56)
  int sr = tid >> 3;
  int sc = (tid & 7) * 8;
  const float* ap = A + (size_t)(m0 + sr)*NN + kbase + sc;

  // B row pointers (global; L2/L3-resident)
  const unsigned short* bp[6];
  #pragma unroll
  for (int ni = 0; ni < 6; ++ni)
    bp[ni] = Bt + (size_t)(wv*96 + ni*16 + l16)*NN + kbase + q*8;

  f32x4 acc[4][6] = {};

  // prologue: stage slice 0
  {
    float4 a0 = *(const float4*)ap;
    float4 a1 = *(const float4*)(ap + 4);
    float xs[8] = {a0.x,a0.y,a0.z,a0.w,a1.x,a1.y,a1.z,a1.w};
    bf16x8 w;
    #pragma unroll
    for (int j = 0; j < 8; ++j) w[j] = (short)f2bf(xs[j]);
    *(bf16x8*)&Asm[0][sr][sc] = w;
  }

  const int NSLICE = (NN/2)/64;   // 64 slices of 64 k
  for (int ks = 0; ks < NSLICE; ++ks) {
    int buf = ks & 1;
    // prefetch next slice to regs
    float4 a0, a1;
    if (ks + 1 < NSLICE) {
      a0 = *(const float4*)(ap + (ks+1)*64);
      a1 = *(const float4*)(ap + (ks+1)*64 + 4);
    }
    __syncthreads();   // Asm[buf] ready
    // compute: 2 sub-iters of k=32
    #pragma unroll
    for (int sub = 0; sub < 2; ++sub) {
      bf16x8 bfr[6];
      #pragma unroll
      for (int ni = 0; ni < 6; ++ni)
        bfr[ni] = *(const bf16x8*)(bp[ni] + ks*64 + sub*32);
      bf16x8 af[4];
      #pragma unroll
      for (int mi = 0; mi < 4; ++mi)
        af[mi] = *(const bf16x8*)&Asm[buf][mi*16 + l16][sub*32 + q*8];
      #pragma unroll
      for (int mi = 0; mi < 4; ++mi)
        #pragma unroll
        for (int ni = 0; ni < 6; ++ni)
          acc[mi][ni] = __builtin_amdgcn_mfma_f32_16x16x32_bf16(af[mi], bfr[ni], acc[mi][ni], 0, 0, 0);
    }
    __syncthreads();   // everyone done with Asm[1-buf] readers from prev iter
    if (ks + 1 < NSLICE) {
      float xs[8] = {a0.x,a0.y,a0.z,a0.w,a1.x,a1.y,a1.z,a1.w};
      bf16x8 w;
      #pragma unroll
      for (int j = 0; j < 8; ++j) w[j] = (short)f2bf(xs[j]);
      *(bf16x8*)&Asm[1-buf][sr][sc] = w;
    }
  }

  // epilogue: write partial
  #pragma unroll
  for (int mi = 0; mi < 4; ++mi) {
    int row = m0 + mi*16 + q*4;
    #pragma unroll
    for (int ni = 0; ni < 6; ++ni) {
      int cn = wv*96 + ni*16 + l16;
      int tt = cn >> 6, h = cn & 63;
      #pragma unroll
      for (int r = 0; r < 4; ++r)
        P[(size_t)tt*NN*64 + (size_t)(row + r)*64 + h] = acc[mi][ni][r];
    }
  }
}

// ---------------- combine partials: sds = coeff * (P0 + P1) ----------------
__global__ __launch_bounds__(256) void sds_combine_kernel(
    const float* __restrict__ P0, const float* __restrict__ P1,
    float* __restrict__ C, const float* __restrict__ coeff)
{
  float cf = coeff[0];
  size_t total = (size_t)TT*NN*64/4;
  for (size_t i = (size_t)blockIdx.x*blockDim.x + threadIdx.x; i < total;
       i += (size_t)gridDim.x*blockDim.x) {
    float4 p0 = ((const float4*)P0)[i];
    float4 p1 = ((const float4*)P1)[i];
    float4 c;
    c.x = cf*(p0.x + p1.x); c.y = cf*(p0.y + p1.y);
    c.z = cf*(p0.z + p1.z); c.w = cf*(p0.w + p1.w);
    ((float4*)C)[i] = c;
  }
}

// ---------------- host ----------------
extern "C" void kernel_launch(void* const* d_in, const int* in_sizes, int n_in,
                              void* d_out, int out_size, void* d_ws, size_t ws_size,
                              hipStream_t stream) {
  const float* node_attrs  = (const float*)d_in[0];
  const float* edge_attrs  = (const float*)d_in[1];
  const float* global_attr = (const float*)d_in[2];
  const float* sp_L        = (const float*)d_in[3];
  const float* coeff       = (const float*)d_in[4];
  const float* w_edge_enc  = (const float*)d_in[5];
  const float* b_edge_enc  = (const float*)d_in[6];
  const float* w_node_enc  = (const float*)d_in[7];
  const float* b_node_enc  = (const float*)d_in[8];
  const float* w_eb        = (const float*)d_in[9];
  const float* b_eb        = (const float*)d_in[10];
  const float* w_nb        = (const float*)d_in[11];
  const float* b_nb        = (const float*)d_in[12];
  const float* w_gb        = (const float*)d_in[13];
  const float* b_gb        = (const float*)d_in[14];
  const float* gru_w_ih    = (const float*)d_in[15];
  const float* gru_w_hh    = (const float*)d_in[16];
  const float* gru_b_ih    = (const float*)d_in[17];
  const float* gru_b_hh    = (const float*)d_in[18];
  const float* w_lout      = (const float*)d_in[19];
  const float* b_lout      = (const float*)d_in[20];
  const int*   edge_index  = (const int*)d_in[21];

  float* ws  = (float*)d_ws;
  float* out = (float*)d_out;
  float* pred_out = out;                              // NN
  float* tds_out  = out + NN;                         // TT*NN*64
  float* sds_out  = tds_out + (size_t)TT*NN*64;       // TT*NN*64
  unsigned short* ebf = (unsigned short*)(ws + OFF_EBF);

  hipLaunchKernelGGL(init_kernel, dim3(1024), dim3(256), 0, stream, ws, global_attr);
  hipLaunchKernelGGL(ebfrag_kernel, dim3(96), dim3(256), 0, stream, w_eb, ebf);
  hipLaunchKernelGGL(gru_his_kernel, dim3(NN/4), dim3(256), 0, stream,
                     node_attrs, gru_w_ih, gru_w_hh, gru_b_ih, gru_b_hh,
                     w_lout, b_lout, pred_out);
  hipLaunchKernelGGL(prep_kernel, dim3(1), dim3(64), 0, stream, w_eb, b_eb, w_nb, b_nb, ws);

  for (int t = 0; t < TT; ++t) {
    float* he_cur  = ws + ((t & 1) ? OFF_HE1 : OFF_HE0);
    float* he_next = ws + ((t & 1) ? OFF_HE0 : OFF_HE1);
    hipLaunchKernelGGL(node_proj_kernel, dim3(NN/16), dim3(256), 0, stream,
                       node_attrs, w_eb, w_node_enc, b_node_enc, ws, t);
    hipLaunchKernelGGL(edge_mfma_kernel, dim3(NE/64), dim3(256), 0, stream,
                       edge_attrs, edge_index, w_edge_enc, b_edge_enc,
                       ebf, ws, he_cur, he_next, t);
    hipLaunchKernelGGL(node_kernel, dim3(NN/16), dim3(256), 0, stream,
                       node_attrs, w_nb, w_node_enc, b_node_enc, ws, tds_out, t);
    hipLaunchKernelGGL(global_prep_kernel, dim3(1), dim3(64), 0, stream,
                       w_gb, b_gb, w_eb, b_eb, w_nb, b_nb, ws);
  }

  // sds GEMM (HE0/HE1 regions are dead after the loop; reuse for partials)
  hipLaunchKernelGGL(sds_mfma_kernel, dim3(2, NN/64), dim3(512), 0, stream,
                     sp_L, (const unsigned short*)(ws + OFF_NEWN),
                     ws + OFF_HE0, ws + OFF_HE1);
  hipLaunchKernelGGL(sds_combine_kernel, dim3(1536), dim3(256), 0, stream,
                     ws + OFF_HE0, ws + OFF_HE1, sds_out, coeff);
}

// Round 5
// 2509.292 us; speedup vs baseline: 2.4169x; 1.1648x over previous
//
#include <hip/hip_runtime.h>
#include <math.h>

#define NN 8192
#define NE 131072
#define TT 12

typedef __attribute__((ext_vector_type(8))) short bf16x8;
typedef __attribute__((ext_vector_type(4))) float f32x4;

// ---------------- workspace layout (float offsets) ----------------
static const size_t OFF_HX    = 0;                                // NN*64
static const size_t OFF_HE0   = OFF_HX    + (size_t)NN*64;        // NE*64 (reused as sds partial P0 after loop)
static const size_t OFF_HE1   = OFF_HE0   + (size_t)NE*64;        // NE*64 (reused as sds partial P1 after loop)
static const size_t OFF_A25   = OFF_HE1   + (size_t)NE*64;        // NN*64
static const size_t OFF_A36   = OFF_A25   + (size_t)NN*64;
static const size_t OFF_CSR   = OFF_A36   + (size_t)NN*64;        // int region (was SENT/RECVD, 2*NN*64 floats)
static const size_t OFF_NEWN  = OFF_CSR   + (size_t)2*NN*64;      // ushort region: newn_T [TT*64][NN] bf16
static const size_t OFF_GL    = OFF_NEWN  + (size_t)NN*TT*32;     // 64
static const size_t OFF_CBE   = OFF_GL    + 64;
static const size_t OFF_CBN   = OFF_CBE   + 64;
static const size_t OFF_ESUM  = OFF_CBN   + 64;
static const size_t OFF_NSUM  = OFF_ESUM  + 64;
static const size_t OFF_EBF   = OFF_NSUM  + 64;                   // ushort region: 24576 shorts

// CSR int-region layout (relative to (int*)(ws + OFF_CSR)):
//   ptr_s[NN+1], ptr_r[NN+1], cnt_s[NN], cnt_r[NN], csr_s[NE], csr_r[NE]
//   total = 294,914 ints << 1,048,576 floats available.

// ---------------- bf16 helpers ----------------
__device__ inline unsigned short f2bf(float x) {
  union { float f; unsigned u; } v; v.f = x;
  unsigned r = v.u + 0x7fffu + ((v.u >> 16) & 1u);
  return (unsigned short)(r >> 16);
}
__device__ inline float bf2f(unsigned short h) {
  union { unsigned u; float f; } v; v.u = ((unsigned)h) << 16;
  return v.f;
}
__device__ inline void split8(const float* x, bf16x8& hi, bf16x8& lo) {
  #pragma unroll
  for (int j = 0; j < 8; ++j) {
    unsigned short h = f2bf(x[j]);
    hi[j] = (short)h;
    lo[j] = (short)f2bf(x[j] - bf2f(h));
  }
}

// ---------------- init: zero hx + he0, copy global_attr -> gl ----------------
__global__ void init_kernel(float* __restrict__ ws, const float* __restrict__ global_attr) {
  size_t total = (size_t)NN*64 + (size_t)NE*64;   // hx and he0 contiguous
  for (size_t i = (size_t)blockIdx.x*blockDim.x + threadIdx.x; i < total;
       i += (size_t)gridDim.x*blockDim.x)
    ws[OFF_HX + i] = 0.f;
  if (blockIdx.x == 0 && threadIdx.x < 64)
    ws[OFF_GL + threadIdx.x] = global_attr[threadIdx.x];
}

// ---------------- prep: cb_e/cb_n for step 0 ----------------
__global__ void prep_kernel(const float* __restrict__ w_eb, const float* __restrict__ b_eb,
                            const float* __restrict__ w_nb, const float* __restrict__ b_nb,
                            float* __restrict__ ws) {
  int h = threadIdx.x;   // 64 threads
  float se = b_eb[h], sn = b_nb[h];
  for (int c = 0; c < 64; ++c) {
    float g = ws[OFF_GL + c];
    se += w_eb[h*448 + 384 + c] * g;
    sn += w_nb[h*320 + 256 + c] * g;
  }
  ws[OFF_CBE + h] = se;
  ws[OFF_CBN + h] = sn;
  ws[OFF_ESUM + h] = 0.f;
  ws[OFF_NSUM + h] = 0.f;
}

// ---------------- CSR build (once per call) ----------------
__global__ void csr_zero_kernel(int* __restrict__ ibase) {
  int* cnt = ibase + 2*(NN+1);
  int i = blockIdx.x*256 + threadIdx.x;
  if (i < 2*NN) cnt[i] = 0;
}

__global__ void csr_hist_kernel(const int* __restrict__ ei, int* __restrict__ ibase) {
  int* cnt_s = ibase + 2*(NN+1);
  int* cnt_r = cnt_s + NN;
  int e = blockIdx.x*256 + threadIdx.x;
  if (e < NE) {
    atomicAdd(&cnt_s[ei[e]], 1);
    atomicAdd(&cnt_r[ei[NE + e]], 1);
  }
}

__global__ __launch_bounds__(256) void csr_scan_kernel(int* __restrict__ ibase) {
  __shared__ int part[257];
  int tid = threadIdx.x;
  int* ptr_s = ibase;
  int* ptr_r = ibase + (NN+1);
  int* cnt_s = ibase + 2*(NN+1);
  int* cnt_r = cnt_s + NN;
  for (int a = 0; a < 2; ++a) {
    int* cnt = a ? cnt_r : cnt_s;
    int* ptr = a ? ptr_r : ptr_s;
    int loc[32];
    int base = tid*32;
    int s = 0;
    #pragma unroll
    for (int i = 0; i < 32; ++i) { loc[i] = s; s += cnt[base + i]; }
    part[tid] = s;
    __syncthreads();
    if (tid == 0) {
      int acc = 0;
      for (int i = 0; i < 256; ++i) { int t = part[i]; part[i] = acc; acc += t; }
      part[256] = acc;
    }
    __syncthreads();
    int off = part[tid];
    #pragma unroll
    for (int i = 0; i < 32; ++i) {
      int v = off + loc[i];
      ptr[base + i] = v;
      cnt[base + i] = v;     // running cursor for fill
    }
    if (tid == 0) ptr[NN] = part[256];
    __syncthreads();
  }
}

__global__ void csr_fill_kernel(const int* __restrict__ ei, int* __restrict__ ibase) {
  int* cnt_s = ibase + 2*(NN+1);
  int* cnt_r = cnt_s + NN;
  int* csr_s = cnt_r + NN;
  int* csr_r = csr_s + NE;
  int e = blockIdx.x*256 + threadIdx.x;
  if (e < NE) {
    int p = atomicAdd(&cnt_s[ei[e]], 1);      csr_s[p] = e;
    int q = atomicAdd(&cnt_r[ei[NE + e]], 1); csr_r[q] = e;
  }
}

// ---------------- build MFMA B-frag table for edge block ----------------
// segs: 0:(eeH,W1H) 1:(eeL,W1H) 2:(eeH,W1L) 3:(heH,W4H) 4:(heL,W4H) 5:(heH,W4L)
__global__ void ebfrag_kernel(const float* __restrict__ w_eb, unsigned short* __restrict__ ebf) {
  int idx = blockIdx.x*256 + threadIdx.x;  // 6*64*64 = 24576
  if (idx >= 24576) return;
  int s = idx >> 12;        // 0..5
  int rem = idx & 4095;
  int k = rem >> 6;         // 0..63
  int n = rem & 63;
  float w = (s < 3) ? w_eb[n*448 + k] : w_eb[n*448 + 192 + k];
  unsigned short h = f2bf(w);
  unsigned short l = f2bf(w - bf2f(h));
  unsigned short val = (s == 2 || s == 5) ? l : h;
  int kh = k >> 5, q = (k >> 3) & 3, j = k & 7;
  int nt = n >> 4, col = n & 15;
  int lane = q*16 + col;
  ebf[(((size_t)(s*2 + kh)*4 + nt)*64 + lane)*8 + j] = val;
}

// ---------------- GRU over T steps + output head -> pred ----------------
__global__ __launch_bounds__(256) void gru_his_kernel(
    const float* __restrict__ node_attrs, const float* __restrict__ w_ih,
    const float* __restrict__ w_hh, const float* __restrict__ b_ih,
    const float* __restrict__ b_hh, const float* __restrict__ w_lout,
    const float* __restrict__ b_lout, float* __restrict__ pred_out)
{
  __shared__ float Whh[192*65];
  __shared__ float wih_s[192], bih_s[192], bhh_s[192], wlo_s[64];
  int tid = threadIdx.x;
  for (int i = tid; i < 192*64; i += 256) {
    int rr = i >> 6, k = i & 63;
    Whh[rr*65 + k] = w_hh[i];
  }
  for (int i = tid; i < 192; i += 256) { wih_s[i] = w_ih[i]; bih_s[i] = b_ih[i]; bhh_s[i] = b_hh[i]; }
  if (tid < 64) wlo_s[tid] = w_lout[tid];
  __syncthreads();
  int lane = tid & 63, wv = tid >> 6;
  int n = blockIdx.x*4 + wv;
  int j = lane;
  float h = 0.f;
  for (int t = 0; t < TT; ++t) {
    float x = node_attrs[t*NN + n];
    float ar = 0.f, az = 0.f, an = 0.f;
    #pragma unroll 16
    for (int k = 0; k < 64; ++k) {
      float hk = __shfl(h, k);
      ar += hk * Whh[j*65 + k];
      az += hk * Whh[(64+j)*65 + k];
      an += hk * Whh[(128+j)*65 + k];
    }
    float xr = x*wih_s[j]      + bih_s[j];
    float xz = x*wih_s[64+j]   + bih_s[64+j];
    float xn = x*wih_s[128+j]  + bih_s[128+j];
    float r  = 1.f/(1.f + expf(-(xr + ar + bhh_s[j])));
    float z  = 1.f/(1.f + expf(-(xz + az + bhh_s[64+j])));
    float nnv = tanhf(xn + r*(an + bhh_s[128+j]));
    h = (1.f - z)*nnv + z*h;
  }
  float v = h * wlo_s[j];
  #pragma unroll
  for (int off = 32; off >= 1; off >>= 1) v += __shfl_xor(v, off);
  if (lane == 0) pred_out[n] = v + b_lout[0];
}

// ---------------- per-step node-side projections A25 = W2@nx+W5@hx, A36 = W3@nx+W6@hx ----------------
__global__ __launch_bounds__(256) void node_proj_kernel(
    const float* __restrict__ node_attrs, const float* __restrict__ w_eb,
    const float* __restrict__ w_node_enc, const float* __restrict__ b_node_enc,
    float* __restrict__ ws, int t)
{
  __shared__ float W2[64*65], W3[64*65], W5[64*65], W6[64*65];
  __shared__ float wne[64], bne[64];
  int tid = threadIdx.x;
  for (int i = tid; i < 64*64; i += 256) {
    int h = i >> 6, c = i & 63;
    W2[h*65+c] = w_eb[h*448 + 64  + c];
    W3[h*65+c] = w_eb[h*448 + 128 + c];
    W5[h*65+c] = w_eb[h*448 + 256 + c];
    W6[h*65+c] = w_eb[h*448 + 320 + c];
  }
  if (tid < 64) { wne[tid] = w_node_enc[tid]; bne[tid] = b_node_enc[tid]; }
  __syncthreads();
  int lane = tid & 63, wv = tid >> 6;
  float* A25 = ws + OFF_A25; float* A36 = ws + OFF_A36;
  float* hx = ws + OFF_HX;
  for (int q = 0; q < 4; ++q) {
    int n = blockIdx.x*16 + wv*4 + q;
    float na = node_attrs[t*NN + n];
    float nx = fmaxf(na*wne[lane] + bne[lane], 0.f);
    float hv = hx[n*64 + lane];
    float a2 = 0.f, a3 = 0.f, a5 = 0.f, a6 = 0.f;
    #pragma unroll 16
    for (int c = 0; c < 64; ++c) {
      float nxc = __shfl(nx, c);
      float hvc = __shfl(hv, c);
      int wi = lane*65 + c;
      a2 += W2[wi]*nxc; a3 += W3[wi]*nxc;
      a5 += W5[wi]*hvc; a6 += W6[wi]*hvc;
    }
    A25[n*64+lane] = a2 + a5; A36[n*64+lane] = a3 + a6;
  }
}

// ---------------- per-step edge block via MFMA (hi/lo split, K=384) + fused ESUM ----------------
__global__ __launch_bounds__(256) void edge_mfma_kernel(
    const float* __restrict__ edge_attrs, const int* __restrict__ edge_index,
    const float* __restrict__ w_edge_enc, const float* __restrict__ b_edge_enc,
    const unsigned short* __restrict__ ebf, float* __restrict__ ws,
    const float* __restrict__ he_cur, float* __restrict__ he_next, int t)
{
  __shared__ unsigned short Bs[12*4*64*8];   // 48 KB, same layout as ebf
  __shared__ float wee_s[64], bee_s[64], cbe_s[64];
  __shared__ float esum_s[64];
  int tid = threadIdx.x;
  for (int i = tid; i < 3072; i += 256)
    ((uint4*)Bs)[i] = ((const uint4*)ebf)[i];
  if (tid < 64) { wee_s[tid]=w_edge_enc[tid]; bee_s[tid]=b_edge_enc[tid]; cbe_s[tid]=ws[OFF_CBE+tid]; esum_s[tid]=0.f; }
  __syncthreads();
  int lane = tid & 63, wv = tid >> 6;
  int m = lane & 15, q = lane >> 4;
  int e0 = blockIdx.x * 64;
  int em = e0 + wv*16 + m;
  // ---- A frags (in registers, no LDS) ----
  float ea = edge_attrs[(size_t)t*NE + em];
  bf16x8 eeH[2], eeL[2], heH[2], heL[2];
  #pragma unroll
  for (int kh = 0; kh < 2; ++kh) {
    float xs[8];
    #pragma unroll
    for (int j = 0; j < 8; ++j) {
      int c = kh*32 + q*8 + j;
      xs[j] = fmaxf(ea*wee_s[c] + bee_s[c], 0.f);
    }
    split8(xs, eeH[kh], eeL[kh]);
    float4 h0 = *(const float4*)(he_cur + (size_t)em*64 + kh*32 + q*8);
    float4 h1 = *(const float4*)(he_cur + (size_t)em*64 + kh*32 + q*8 + 4);
    float hs[8] = {h0.x,h0.y,h0.z,h0.w,h1.x,h1.y,h1.z,h1.w};
    split8(hs, heH[kh], heL[kh]);
  }
  // ---- MFMA: 12 K-blocks x 4 N-tiles ----
  f32x4 acc[4] = {};
  #pragma unroll
  for (int s = 0; s < 6; ++s) {
    #pragma unroll
    for (int kh = 0; kh < 2; ++kh) {
      bf16x8 a = (s==0||s==2) ? eeH[kh] : (s==1) ? eeL[kh] : (s==4) ? heL[kh] : heH[kh];
      const bf16x8* bp = (const bf16x8*)(Bs + (size_t)((s*2+kh)*4*64)*8);
      #pragma unroll
      for (int nt = 0; nt < 4; ++nt) {
        bf16x8 b = bp[nt*64 + lane];
        acc[nt] = __builtin_amdgcn_mfma_f32_16x16x32_bf16(a, b, acc[nt], 0, 0, 0);
      }
    }
  }
  // ---- epilogue: gathers + relu + stores + fused esum (NO scatter atomics) ----
  const int* sendi = edge_index;
  const int* recvi = edge_index + NE;
  const float* A25 = ws + OFF_A25;
  const float* A36 = ws + OFF_A36;
  int col = lane & 15;
  float part[4] = {0.f, 0.f, 0.f, 0.f};
  #pragma unroll
  for (int r = 0; r < 4; ++r) {
    int e = e0 + wv*16 + q*4 + r;
    int se = sendi[e], re = recvi[e];
    #pragma unroll
    for (int nt = 0; nt < 4; ++nt) {
      int h = nt*16 + col;
      float v = acc[nt][r] + A25[(size_t)se*64 + h] + A36[(size_t)re*64 + h] + cbe_s[h];
      v = fmaxf(v, 0.f);
      he_next[(size_t)e*64 + h] = v;
      part[nt] += v;
    }
  }
  #pragma unroll
  for (int nt = 0; nt < 4; ++nt) {
    part[nt] += __shfl_xor(part[nt], 16);
    part[nt] += __shfl_xor(part[nt], 32);
  }
  if (q == 0) {
    #pragma unroll
    for (int nt = 0; nt < 4; ++nt)
      atomicAdd(&esum_s[nt*16 + col], part[nt]);
  }
  __syncthreads();
  if (tid < 64) atomicAdd(&ws[OFF_ESUM + tid], esum_s[tid]);
}

// ---------------- per-step node block: CSR gather + MLP + tds + hx + newn_T + NSUM ----------------
__global__ __launch_bounds__(256) void node_kernel(
    const float* __restrict__ node_attrs, const float* __restrict__ w_nb,
    const float* __restrict__ w_node_enc, const float* __restrict__ b_node_enc,
    float* __restrict__ ws, float* __restrict__ tds_out,
    const float* __restrict__ he, int t)
{
  __shared__ float B1[64*65], B2[64*65], B3[64*65], B4[64*65];
  __shared__ float wne[64], bne[64], cbn[64];
  __shared__ float nsum_s[4][64];
  int tid = threadIdx.x;
  for (int i = tid; i < 64*64; i += 256) {
    int h = i >> 6, c = i & 63;
    B1[h*65+c] = w_nb[h*320 + c];          // nx
    B2[h*65+c] = w_nb[h*320 + 64  + c];    // hx
    B3[h*65+c] = w_nb[h*320 + 128 + c];    // recvd
    B4[h*65+c] = w_nb[h*320 + 192 + c];    // sent
  }
  if (tid < 64) { wne[tid] = w_node_enc[tid]; bne[tid] = b_node_enc[tid]; cbn[tid] = ws[OFF_CBN + tid]; }
  __syncthreads();
  int lane = tid & 63, wv = tid >> 6;
  float* hx = ws + OFF_HX;
  const int* ibase = (const int*)(ws + OFF_CSR);
  const int* ptr_s = ibase;
  const int* ptr_r = ibase + (NN+1);
  const int* csr_s = ibase + 2*(NN+1) + 2*NN;
  const int* csr_r = csr_s + NE;
  unsigned short* newnT = (unsigned short*)(ws + OFF_NEWN);
  float npart = 0.f;
  for (int q = 0; q < 4; ++q) {
    int n = blockIdx.x*16 + wv*4 + q;
    // ---- CSR segment-sums (replaces scatter atomics) ----
    float st = 0.f;
    {
      int i = ptr_s[n], end = ptr_s[n+1];
      for (; i + 4 <= end; i += 4) {
        int e0 = csr_s[i], e1 = csr_s[i+1], e2 = csr_s[i+2], e3 = csr_s[i+3];
        float v0 = he[(size_t)e0*64 + lane], v1 = he[(size_t)e1*64 + lane];
        float v2 = he[(size_t)e2*64 + lane], v3 = he[(size_t)e3*64 + lane];
        st += (v0 + v1) + (v2 + v3);
      }
      for (; i < end; ++i) st += he[(size_t)csr_s[i]*64 + lane];
    }
    float rc = 0.f;
    {
      int i = ptr_r[n], end = ptr_r[n+1];
      for (; i + 4 <= end; i += 4) {
        int e0 = csr_r[i], e1 = csr_r[i+1], e2 = csr_r[i+2], e3 = csr_r[i+3];
        float v0 = he[(size_t)e0*64 + lane], v1 = he[(size_t)e1*64 + lane];
        float v2 = he[(size_t)e2*64 + lane], v3 = he[(size_t)e3*64 + lane];
        rc += (v0 + v1) + (v2 + v3);
      }
      for (; i < end; ++i) rc += he[(size_t)csr_r[i]*64 + lane];
    }
    // ---- node MLP ----
    float na = node_attrs[t*NN + n];
    float nx = fmaxf(na*wne[lane] + bne[lane], 0.f);
    float hv = hx[n*64 + lane];
    float acc = 0.f;
    #pragma unroll 16
    for (int c = 0; c < 64; ++c) {
      float nxc = __shfl(nx, c);
      float hvc = __shfl(hv, c);
      float rcc = __shfl(rc, c);
      float stc = __shfl(st, c);
      int wi = lane*65 + c;
      acc += B1[wi]*nxc + B2[wi]*hvc + B3[wi]*rcc + B4[wi]*stc;
    }
    acc += cbn[lane];
    float nn = fmaxf(acc, 0.f);
    tds_out[(size_t)t*NN*64 + (size_t)n*64 + lane] = nn - hv;
    hx[n*64 + lane] = nn;
    newnT[(size_t)(t*64 + lane)*NN + n] = f2bf(nn);   // transposed bf16 for sds GEMM
    npart += nn;
  }
  nsum_s[wv][lane] = npart;
  __syncthreads();
  if (tid < 64)
    atomicAdd(&ws[OFF_NSUM + tid],
              nsum_s[0][tid] + nsum_s[1][tid] + nsum_s[2][tid] + nsum_s[3][tid]);
}

// ---------------- per-step global block (+ next step cb prep + zero sums) ----------------
__global__ void global_prep_kernel(
    const float* __restrict__ w_gb, const float* __restrict__ b_gb,
    const float* __restrict__ w_eb, const float* __restrict__ b_eb,
    const float* __restrict__ w_nb, const float* __restrict__ b_nb,
    float* __restrict__ ws)
{
  int h = threadIdx.x;   // 64 threads
  __shared__ float gin[192];
  __shared__ float gs[64];
  gin[h]       = ws[OFF_NSUM + h] * (1.0f/NN);
  gin[64 + h]  = ws[OFF_ESUM + h] * (1.0f/NE);
  gin[128 + h] = ws[OFF_GL + h];
  __syncthreads();
  float a = b_gb[h];
  for (int c = 0; c < 192; ++c) a += w_gb[h*192 + c] * gin[c];
  float g = fmaxf(a, 0.f);
  gs[h] = g;
  __syncthreads();
  ws[OFF_GL + h] = g;
  float se = b_eb[h], sn = b_nb[h];
  for (int c = 0; c < 64; ++c) {
    float gc = gs[c];
    se += w_eb[h*448 + 384 + c] * gc;
    sn += w_nb[h*320 + 256 + c] * gc;
  }
  ws[OFF_CBE + h] = se;
  ws[OFF_CBN + h] = sn;
  ws[OFF_ESUM + h] = 0.f;
  ws[OFF_NSUM + h] = 0.f;
}

// ---------------- sds GEMM via MFMA, split-K=2, A read once ----------------
__global__ __launch_bounds__(512) void sds_mfma_kernel(
    const float* __restrict__ A, const unsigned short* __restrict__ Bt,
    float* __restrict__ P0, float* __restrict__ P1)
{
  __shared__ unsigned short Asm[2][64][72];
  int tid = threadIdx.x;
  int lane = tid & 63, wv = tid >> 6;
  int q = lane >> 4, l16 = lane & 15;
  int m0 = blockIdx.y * 64;
  int kbase = blockIdx.x * (NN/2);
  float* P = (blockIdx.x == 0) ? P0 : P1;

  int sr = tid >> 3;
  int sc = (tid & 7) * 8;
  const float* ap = A + (size_t)(m0 + sr)*NN + kbase + sc;

  const unsigned short* bp[6];
  #pragma unroll
  for (int ni = 0; ni < 6; ++ni)
    bp[ni] = Bt + (size_t)(wv*96 + ni*16 + l16)*NN + kbase + q*8;

  f32x4 acc[4][6] = {};

  {
    float4 a0 = *(const float4*)ap;
    float4 a1 = *(const float4*)(ap + 4);
    float xs[8] = {a0.x,a0.y,a0.z,a0.w,a1.x,a1.y,a1.z,a1.w};
    bf16x8 w;
    #pragma unroll
    for (int j = 0; j < 8; ++j) w[j] = (short)f2bf(xs[j]);
    *(bf16x8*)&Asm[0][sr][sc] = w;
  }

  const int NSLICE = (NN/2)/64;
  for (int ks = 0; ks < NSLICE; ++ks) {
    int buf = ks & 1;
    float4 a0, a1;
    if (ks + 1 < NSLICE) {
      a0 = *(const float4*)(ap + (ks+1)*64);
      a1 = *(const float4*)(ap + (ks+1)*64 + 4);
    }
    __syncthreads();
    #pragma unroll
    for (int sub = 0; sub < 2; ++sub) {
      bf16x8 bfr[6];
      #pragma unroll
      for (int ni = 0; ni < 6; ++ni)
        bfr[ni] = *(const bf16x8*)(bp[ni] + ks*64 + sub*32);
      bf16x8 af[4];
      #pragma unroll
      for (int mi = 0; mi < 4; ++mi)
        af[mi] = *(const bf16x8*)&Asm[buf][mi*16 + l16][sub*32 + q*8];
      #pragma unroll
      for (int mi = 0; mi < 4; ++mi)
        #pragma unroll
        for (int ni = 0; ni < 6; ++ni)
          acc[mi][ni] = __builtin_amdgcn_mfma_f32_16x16x32_bf16(af[mi], bfr[ni], acc[mi][ni], 0, 0, 0);
    }
    __syncthreads();
    if (ks + 1 < NSLICE) {
      float xs[8] = {a0.x,a0.y,a0.z,a0.w,a1.x,a1.y,a1.z,a1.w};
      bf16x8 w;
      #pragma unroll
      for (int j = 0; j < 8; ++j) w[j] = (short)f2bf(xs[j]);
      *(bf16x8*)&Asm[1-buf][sr][sc] = w;
    }
  }

  #pragma unroll
  for (int mi = 0; mi < 4; ++mi) {
    int row = m0 + mi*16 + q*4;
    #pragma unroll
    for (int ni = 0; ni < 6; ++ni) {
      int cn = wv*96 + ni*16 + l16;
      int tt = cn >> 6, h = cn & 63;
      #pragma unroll
      for (int r = 0; r < 4; ++r)
        P[(size_t)tt*NN*64 + (size_t)(row + r)*64 + h] = acc[mi][ni][r];
    }
  }
}

// ---------------- combine partials: sds = coeff * (P0 + P1) ----------------
__global__ __launch_bounds__(256) void sds_combine_kernel(
    const float* __restrict__ P0, const float* __restrict__ P1,
    float* __restrict__ C, const float* __restrict__ coeff)
{
  float cf = coeff[0];
  size_t total = (size_t)TT*NN*64/4;
  for (size_t i = (size_t)blockIdx.x*blockDim.x + threadIdx.x; i < total;
       i += (size_t)gridDim.x*blockDim.x) {
    float4 p0 = ((const float4*)P0)[i];
    float4 p1 = ((const float4*)P1)[i];
    float4 c;
    c.x = cf*(p0.x + p1.x); c.y = cf*(p0.y + p1.y);
    c.z = cf*(p0.z + p1.z); c.w = cf*(p0.w + p1.w);
    ((float4*)C)[i] = c;
  }
}

// ---------------- host ----------------
extern "C" void kernel_launch(void* const* d_in, const int* in_sizes, int n_in,
                              void* d_out, int out_size, void* d_ws, size_t ws_size,
                              hipStream_t stream) {
  const float* node_attrs  = (const float*)d_in[0];
  const float* edge_attrs  = (const float*)d_in[1];
  const float* global_attr = (const float*)d_in[2];
  const float* sp_L        = (const float*)d_in[3];
  const float* coeff       = (const float*)d_in[4];
  const float* w_edge_enc  = (const float*)d_in[5];
  const float* b_edge_enc  = (const float*)d_in[6];
  const float* w_node_enc  = (const float*)d_in[7];
  const float* b_node_enc  = (const float*)d_in[8];
  const float* w_eb        = (const float*)d_in[9];
  const float* b_eb        = (const float*)d_in[10];
  const float* w_nb        = (const float*)d_in[11];
  const float* b_nb        = (const float*)d_in[12];
  const float* w_gb        = (const float*)d_in[13];
  const float* b_gb        = (const float*)d_in[14];
  const float* gru_w_ih    = (const float*)d_in[15];
  const float* gru_w_hh    = (const float*)d_in[16];
  const float* gru_b_ih    = (const float*)d_in[17];
  const float* gru_b_hh    = (const float*)d_in[18];
  const float* w_lout      = (const float*)d_in[19];
  const float* b_lout      = (const float*)d_in[20];
  const int*   edge_index  = (const int*)d_in[21];

  float* ws  = (float*)d_ws;
  float* out = (float*)d_out;
  float* pred_out = out;                              // NN
  float* tds_out  = out + NN;                         // TT*NN*64
  float* sds_out  = tds_out + (size_t)TT*NN*64;       // TT*NN*64
  unsigned short* ebf = (unsigned short*)(ws + OFF_EBF);
  int* ibase = (int*)(ws + OFF_CSR);

  hipLaunchKernelGGL(init_kernel, dim3(1024), dim3(256), 0, stream, ws, global_attr);
  hipLaunchKernelGGL(ebfrag_kernel, dim3(96), dim3(256), 0, stream, w_eb, ebf);
  hipLaunchKernelGGL(gru_his_kernel, dim3(NN/4), dim3(256), 0, stream,
                     node_attrs, gru_w_ih, gru_w_hh, gru_b_ih, gru_b_hh,
                     w_lout, b_lout, pred_out);
  hipLaunchKernelGGL(prep_kernel, dim3(1), dim3(64), 0, stream, w_eb, b_eb, w_nb, b_nb, ws);

  // CSR build (once per call)
  hipLaunchKernelGGL(csr_zero_kernel, dim3((2*NN+255)/256), dim3(256), 0, stream, ibase);
  hipLaunchKernelGGL(csr_hist_kernel, dim3(NE/256), dim3(256), 0, stream, edge_index, ibase);
  hipLaunchKernelGGL(csr_scan_kernel, dim3(1), dim3(256), 0, stream, ibase);
  hipLaunchKernelGGL(csr_fill_kernel, dim3(NE/256), dim3(256), 0, stream, edge_index, ibase);

  for (int t = 0; t < TT; ++t) {
    float* he_cur  = ws + ((t & 1) ? OFF_HE1 : OFF_HE0);
    float* he_next = ws + ((t & 1) ? OFF_HE0 : OFF_HE1);
    hipLaunchKernelGGL(node_proj_kernel, dim3(NN/16), dim3(256), 0, stream,
                       node_attrs, w_eb, w_node_enc, b_node_enc, ws, t);
    hipLaunchKernelGGL(edge_mfma_kernel, dim3(NE/64), dim3(256), 0, stream,
                       edge_attrs, edge_index, w_edge_enc, b_edge_enc,
                       ebf, ws, he_cur, he_next, t);
    hipLaunchKernelGGL(node_kernel, dim3(NN/16), dim3(256), 0, stream,
                       node_attrs, w_nb, w_node_enc, b_node_enc, ws, tds_out, he_next, t);
    hipLaunchKernelGGL(global_prep_kernel, dim3(1), dim3(64), 0, stream,
                       w_gb, b_gb, w_eb, b_eb, w_nb, b_nb, ws);
  }

  // sds GEMM (HE0/HE1 regions are dead after the loop; reuse for partials)
  hipLaunchKernelGGL(sds_mfma_kernel, dim3(2, NN/64), dim3(512), 0, stream,
                     sp_L, (const unsigned short*)(ws + OFF_NEWN),
                     ws + OFF_HE0, ws + OFF_HE1);
  hipLaunchKernelGGL(sds_combine_kernel, dim3(1536), dim3(256), 0, stream,
                     ws + OFF_HE0, ws + OFF_HE1, sds_out, coeff);
}